// Round 9
// baseline (4375.107 us; speedup 1.0000x reference)
//
#include <hip/hip_runtime.h>

#define B_ 4
#define N_ 16384
#define D_ 125
#define S_ 2048
#define K_ 16
#define C0_ 128
#define C1_ 128
#define C2_ 256
#define NSLOT 64

typedef float v2f __attribute__((ext_vector_type(2)));

// Opaque-ify a float so the compiler cannot rematerialize it from memory.
__device__ __forceinline__ void pin(float& x) { asm volatile("" : "+v"(x)); }

// elementwise max on v2f -> v_pk_max_f32 (exact, order-free)
__device__ __forceinline__ v2f v2max(v2f a, v2f b) {
  v2f r;
  r.x = fmaxf(a.x, b.x);
  r.y = fmaxf(a.y, b.y);
  return r;
}

// ---------------------------------------------------------------------------
// 64-bit max reduction step via DPP (pure VALU, no ds_bpermute).
// Keys are positive finite doubles -> fmax == u64 max. old=own word +
// bound_ctrl=false => masked lanes yield own value (max identity).
// After row_shr 1/2/4/8 + row_bcast15(0xa) + row_bcast31(0xc), lane 63
// holds the wave max. (HW-verified R5/R6/R8)
// ---------------------------------------------------------------------------
template <int CTRL, int RMASK>
__device__ __forceinline__ double dppmax(double k) {
  const long long kb = __double_as_longlong(k);
  const int lo = (int)(kb & 0xffffffffll);
  const int hi = (int)(((unsigned long long)kb) >> 32);
  const int plo = __builtin_amdgcn_update_dpp(lo, lo, CTRL, RMASK, 0xf, false);
  const int phi = __builtin_amdgcn_update_dpp(hi, hi, CTRL, RMASK, 0xf, false);
  const double p =
      __longlong_as_double(((long long)phi << 32) | (unsigned int)plo);
  return fmax(k, p);
}

// ---------------------------------------------------------------------------
// FPS v9: 512 threads (8 waves), 32 points/thread (16 v2f pairs).
// R8 post-mortem: the v8 structure is right but 16 waves multiply every
// per-wave cost on the serial barrier-to-barrier path (unconditional issue
// 4-deep/SIMD, 16 serialized ds_max_u64, 16 barrier arrivals). v9 halves
// the wave count: unconditional issue and atomic depth halve; VGPR cost of
// point data doubles (~190 total, fits 256 @ waves_per_eu(2,2), no spill).
// Algorithm unchanged from the R6/R8-verified skeleton: Morton sort (same
// 16^3 cells), per-thread bbox prune with exact lower bound L (same
// rounding shape, L <= fl(dist^2)), single barrier, tagged ds_max_u64
// publish key=(s<<52)|(f32bits<<20)|(inv<<4)|wave_id, per-wave coords
// slots, f64-punned DPP wave reduce, max3 box test, pk_max lane tree,
// setprio around the active branch. Selection by (value, ORIGINAL index)
// is slot-permutation-invariant -> trajectory bit-exact (jnp.argmax
// first-match semantics preserved).
// ---------------------------------------------------------------------------
__global__ __attribute__((amdgpu_flat_work_group_size(512, 512),
                          amdgpu_waves_per_eu(2, 2)))
void fps_kernel(const float* __restrict__ xyz, float* __restrict__ new_xyz,
                float* __restrict__ sortbuf) {
#pragma clang fp contract(off)
  const int b = blockIdx.x;
  const float* X = xyz + (size_t)b * N_ * 3;
  float* SB = sortbuf + (size_t)b * 3 * N_;
  const int t = threadIdx.x;
  constexpr int PAIRS = N_ / 512 / 2;  // 16 pairs = 32 points/thread
  const int base = t * (2 * PAIRS);    // orig-load base AND sorted slot base

  __shared__ unsigned int s_hist[4096];          // 16 KB (sort only)
  __shared__ float s_bb[8][8];                   // wave bboxes (sort only)
  __shared__ unsigned int s_wsum[8];             // scan wave totals
  __shared__ unsigned short s_sidx[N_];          // 32 KB: slot -> orig index
  __shared__ unsigned long long s_k1[2];         // dbuf block-winner key
  __shared__ __align__(16) float4 s_cc[2][8];    // per-wave candidate coords

  // ---- load my 32 original points: 24 x float4 = 96 contiguous floats ----
  float arr[96];
  {
    float4* a4 = (float4*)arr;
#pragma unroll
    for (int i = 0; i < 24; ++i) a4[i] = *(const float4*)(X + base * 3 + 4 * i);
  }
  // ---- block bbox ----
  float lx0 = arr[0], lx1 = arr[0], ly0 = arr[1], ly1 = arr[1];
  float lz0 = arr[2], lz1 = arr[2];
#pragma unroll
  for (int p = 1; p < 32; ++p) {
    lx0 = fminf(lx0, arr[3 * p + 0]); lx1 = fmaxf(lx1, arr[3 * p + 0]);
    ly0 = fminf(ly0, arr[3 * p + 1]); ly1 = fmaxf(ly1, arr[3 * p + 1]);
    lz0 = fminf(lz0, arr[3 * p + 2]); lz1 = fmaxf(lz1, arr[3 * p + 2]);
  }
#pragma unroll
  for (int off = 32; off > 0; off >>= 1) {
    lx0 = fminf(lx0, __shfl_xor(lx0, off)); lx1 = fmaxf(lx1, __shfl_xor(lx1, off));
    ly0 = fminf(ly0, __shfl_xor(ly0, off)); ly1 = fmaxf(ly1, __shfl_xor(ly1, off));
    lz0 = fminf(lz0, __shfl_xor(lz0, off)); lz1 = fmaxf(lz1, __shfl_xor(lz1, off));
  }
  if ((t & 63) == 0) {
    const int w = t >> 6;
    s_bb[w][0] = lx0; s_bb[w][1] = lx1; s_bb[w][2] = ly0;
    s_bb[w][3] = ly1; s_bb[w][4] = lz0; s_bb[w][5] = lz1;
  }
  for (int i = t; i < 4096; i += 512) s_hist[i] = 0u;
  if (t == 0) { s_k1[0] = 0ull; s_k1[1] = 0ull; }
  __syncthreads();
  float gx0 = s_bb[0][0], gx1 = s_bb[0][1], gy0 = s_bb[0][2];
  float gy1 = s_bb[0][3], gz0 = s_bb[0][4], gz1 = s_bb[0][5];
#pragma unroll
  for (int w = 1; w < 8; ++w) {
    gx0 = fminf(gx0, s_bb[w][0]); gx1 = fmaxf(gx1, s_bb[w][1]);
    gy0 = fminf(gy0, s_bb[w][2]); gy1 = fmaxf(gy1, s_bb[w][3]);
    gz0 = fminf(gz0, s_bb[w][4]); gz1 = fmaxf(gz1, s_bb[w][5]);
  }
  const float ivx = (gx1 > gx0) ? 16.0f / (gx1 - gx0) : 0.0f;
  const float ivy = (gy1 > gy0) ? 16.0f / (gy1 - gy0) : 0.0f;
  const float ivz = (gz1 > gz0) ? 16.0f / (gz1 - gz0) : 0.0f;
  // ---- Morton cell per point + histogram ----
  int cell[32];
#pragma unroll
  for (int p = 0; p < 32; ++p) {
    int qx = min(15, (int)((arr[3 * p + 0] - gx0) * ivx));
    int qy = min(15, (int)((arr[3 * p + 1] - gy0) * ivy));
    int qz = min(15, (int)((arr[3 * p + 2] - gz0) * ivz));
    int mx = (qx & 1) | ((qx & 2) << 2) | ((qx & 4) << 4) | ((qx & 8) << 6);
    int my = (qy & 1) | ((qy & 2) << 2) | ((qy & 4) << 4) | ((qy & 8) << 6);
    int mz = (qz & 1) | ((qz & 2) << 2) | ((qz & 4) << 4) | ((qz & 8) << 6);
    cell[p] = mx | (my << 1) | (mz << 2);
    atomicAdd(&s_hist[cell[p]], 1u);
  }
  __syncthreads();
  // ---- exclusive scan of 4096 bins (8 per thread, thread-major order) ----
  {
    unsigned int c[8];
    unsigned int tsum = 0u;
#pragma unroll
    for (int k = 0; k < 8; ++k) { c[k] = s_hist[8 * t + k]; tsum += c[k]; }
    unsigned int incl = tsum;
#pragma unroll
    for (int off = 1; off < 64; off <<= 1) {
      unsigned int nv = __shfl_up(incl, off);
      if ((t & 63) >= off) incl += nv;
    }
    if ((t & 63) == 63) s_wsum[t >> 6] = incl;
    __syncthreads();
    unsigned int wpre = 0;
    const int myw = t >> 6;
    for (int w = 0; w < myw; ++w) wpre += s_wsum[w];
    unsigned int run = wpre + incl - tsum;
#pragma unroll
    for (int k = 0; k < 8; ++k) {
      s_hist[8 * t + k] = run;
      run += c[k];
    }
  }
  __syncthreads();
  // ---- scatter points + orig indices ----
#pragma unroll
  for (int p = 0; p < 32; ++p) {
    const unsigned int slot = atomicAdd(&s_hist[cell[p]], 1u);
    SB[slot]          = arr[3 * p + 0];
    SB[N_ + slot]     = arr[3 * p + 1];
    SB[2 * N_ + slot] = arr[3 * p + 2];
    s_sidx[slot] = (unsigned short)(base + p);
  }
  __threadfence();
  __syncthreads();
  __threadfence();

  // ---- reload sorted points (coalesced float4) ----
  v2f px[PAIRS], py[PAIRS], pz[PAIRS], d[PAIRS];
  {
    float4 xa[8], ya[8], za[8];
#pragma unroll
    for (int i = 0; i < 8; ++i) {
      xa[i] = *(const float4*)(SB + base + 4 * i);
      ya[i] = *(const float4*)(SB + N_ + base + 4 * i);
      za[i] = *(const float4*)(SB + 2 * N_ + base + 4 * i);
    }
    const float* xf = (const float*)xa;
    const float* yf = (const float*)ya;
    const float* zf = (const float*)za;
#pragma unroll
    for (int j = 0; j < PAIRS; ++j) {
      px[j] = (v2f){xf[2 * j], xf[2 * j + 1]};
      py[j] = (v2f){yf[2 * j], yf[2 * j + 1]};
      pz[j] = (v2f){zf[2 * j], zf[2 * j + 1]};
      d[j] = (v2f){1e10f, 1e10f};
    }
  }
  // inverted original indices, u16-packed: ~word == (0xFFFF-hi, 0xFFFF-lo)
  // orig < 16384 so inv in [0xC000, 0xFFFF] and is globally unique.
  unsigned int invw[PAIRS];
  {
    const unsigned int* SI = (const unsigned int*)&s_sidx[base];
#pragma unroll
    for (int j = 0; j < PAIRS; ++j) invw[j] = ~SI[j];
  }
  // per-thread bbox of my (now spatially-coherent) 32 points
  float bx0 = 1e30f, bx1 = -1e30f, by0 = 1e30f, by1 = -1e30f;
  float bz0 = 1e30f, bz1 = -1e30f;
#pragma unroll
  for (int j = 0; j < PAIRS; ++j) {
    bx0 = fminf(bx0, fminf(px[j].x, px[j].y));
    bx1 = fmaxf(bx1, fmaxf(px[j].x, px[j].y));
    by0 = fminf(by0, fminf(py[j].x, py[j].y));
    by1 = fmaxf(by1, fmaxf(py[j].x, py[j].y));
    bz0 = fminf(bz0, fminf(pz[j].x, pz[j].y));
    bz1 = fmaxf(bz1, fmaxf(pz[j].x, pz[j].y));
  }
  // Pin coordinates into registers (blocks rematerialization from memory).
#pragma unroll
  for (int j = 0; j < PAIRS; ++j) {
    float a0 = px[j].x, a1 = px[j].y;
    float b0 = py[j].x, b1 = py[j].y;
    float c0 = pz[j].x, c1 = pz[j].y;
    pin(a0); pin(a1); pin(b0); pin(b1); pin(c0); pin(c1);
    px[j] = (v2f){a0, a1};
    py[j] = (v2f){b0, b1};
    pz[j] = (v2f){c0, c1};
  }
  float cx = X[0], cy = X[1], cz = X[2];  // centroid 0 (orig point 0)
  float tmax = 1e10f;                     // exact max of this lane's d[]
  unsigned long long keylow = 0ull;       // cached wave-winner low-52 key
  bool iwin = false;                      // am I my wave's winner lane?
  float ccx = 0.f, ccy = 0.f, ccz = 0.f;  // cached lane candidate coords
  float cap_x = 0.f, cap_y = 0.f, cap_z = 0.f;
  const unsigned int wid = (unsigned int)(t >> 6);
  for (int s = 0; s < S_; ++s) {
    if (((s - t) & 511) == 0) { cap_x = cx; cap_y = cy; cap_z = cz; }
    if ((s & 511) == 511) {  // epoch flush: 512 coalesced centroids
      const int o = (b * S_ + (s & ~511) + t) * 3;
      new_xyz[o + 0] = cap_x;
      new_xyz[o + 1] = cap_y;
      new_xyz[o + 2] = cap_z;
    }
    if (s == S_ - 1) break;  // last index needs no further update
    const int buf = s & 1;
    // ---- exact box lower bound, same rounding shape as the distance ----
    const float mx = fmaxf(fmaxf(bx0 - cx, cx - bx1), 0.0f);
    const float my = fmaxf(fmaxf(by0 - cy, cy - by1), 0.0f);
    const float mz = fmaxf(fmaxf(bz0 - cz, cz - bz1), 0.0f);
    const float L = (mx * mx + my * my) + mz * mz;  // L <= fl(dist^2) for all
    if (__any(L < tmax)) {
      __builtin_amdgcn_s_setprio(1);  // favor the critical active wave (T5)
      // ---- value update (packed, register-resident; no in-loop max) ----
      const v2f c2x = {cx, cx}, c2y = {cy, cy}, c2z = {cz, cz};
#pragma unroll
      for (int j = 0; j < PAIRS; ++j) {
        v2f dx = px[j] - c2x;
        v2f dy = py[j] - c2y;
        v2f dz = pz[j] - c2z;
        v2f sq = (dx * dx + dy * dy) + dz * dz;  // exact ref order
        v2f dm;
        dm.x = fminf(d[j].x, sq.x);
        dm.y = fminf(d[j].y, sq.y);
        d[j] = dm;
      }
      // ---- lane max via pk_max tree (max exact & order-free) ----
      v2f m[8];
#pragma unroll
      for (int j = 0; j < 8; ++j) m[j] = v2max(d[2 * j], d[2 * j + 1]);
      const v2f n0 = v2max(m[0], m[1]);
      const v2f n1 = v2max(m[2], m[3]);
      const v2f n2 = v2max(m[4], m[5]);
      const v2f n3 = v2max(m[6], m[7]);
      const v2f q0 = v2max(n0, n1);
      const v2f q1 = v2max(n2, n3);
      const v2f q = v2max(q0, q1);
      const float lmax = fmaxf(q.x, q.y);
      tmax = lmax;
      // ---- lane tie-break in registers: max inv == min orig idx ----
      unsigned int binv = 0u;
#pragma unroll
      for (int j = 0; j < PAIRS; ++j) {
        const unsigned int lo = invw[j] & 0xFFFFu;
        const unsigned int hi = invw[j] >> 16;
        if (d[j].x == lmax) binv = max(binv, lo);
        if (d[j].y == lmax) binv = max(binv, hi);
      }
      // ---- lane candidate coords (unique inv match) ----
#pragma unroll
      for (int j = 0; j < PAIRS; ++j) {
        const unsigned int lo = invw[j] & 0xFFFFu;
        const unsigned int hi = invw[j] >> 16;
        if (lo == binv) { ccx = px[j].x; ccy = py[j].x; ccz = pz[j].x; }
        if (hi == binv) { ccx = px[j].y; ccy = py[j].y; ccz = pz[j].y; }
      }
      // ---- low-52 key; DPP max reduce (pure VALU, active waves only) ----
      const unsigned long long k52 =
          ((unsigned long long)__float_as_uint(lmax) << 20) |
          (unsigned long long)((binv << 4) | wid);
      double dk = __longlong_as_double((long long)k52);
      dk = dppmax<0x111, 0xf>(dk);  // row_shr:1
      dk = dppmax<0x112, 0xf>(dk);  // row_shr:2
      dk = dppmax<0x114, 0xf>(dk);  // row_shr:4
      dk = dppmax<0x118, 0xf>(dk);  // row_shr:8 -> lane15+16r = row max
      dk = dppmax<0x142, 0xa>(dk);  // row_bcast15 rows 1,3
      dk = dppmax<0x143, 0xc>(dk);  // row_bcast31 rows 2,3 -> lane63 = wave max
      const long long kb = __double_as_longlong(dk);
      const int rlo = __builtin_amdgcn_readlane((int)(kb & 0xffffffffll), 63);
      const int rhi =
          __builtin_amdgcn_readlane((int)(((unsigned long long)kb) >> 32), 63);
      const unsigned long long wk52 =
          ((unsigned long long)(unsigned int)rhi << 32) | (unsigned int)rlo;
      iwin = (k52 == wk52);
      keylow = wk52;
      __builtin_amdgcn_s_setprio(0);
    }
    // ---- winner lane publishes tagged key + coords (O(1) per wave) ----
    // skipped wave: candidate provably unchanged; re-tag cached keylow.
    if (iwin) {
      atomicMax(&s_k1[buf], ((unsigned long long)s << 52) | keylow);
      s_cc[buf][wid] = make_float4(ccx, ccy, ccz, 0.f);
    }
    __syncthreads();
    // ---- block winner: one uniform b64 read + one uniform b128 read ----
    const unsigned long long bk = s_k1[buf];
    const int w_win = (int)(bk & 15ull);
    const float4 cc = s_cc[buf][w_win];
    cx = cc.x; cy = cc.y; cz = cc.z;
  }
}

// ---------------------------------------------------------------------------
// kNN: one block (256 thr) per query. Distances in LDS; 16 rounds of
// block-min with winner-only local rescan. Set semantics (order irrelevant).
// ---------------------------------------------------------------------------
__global__ __launch_bounds__(256) void knn_kernel(const float* __restrict__ xyz,
                                                  const float* __restrict__ new_xyz,
                                                  int* __restrict__ knn_idx) {
  const int q = blockIdx.x;  // b*S + s
  const int b = q / S_;
  __shared__ float sd[N_];  // 64 KB
  __shared__ float s_minv[4];
  __shared__ int s_mini[4];
  __shared__ int s_win;
  const int t = threadIdx.x;
  const float qx = new_xyz[q * 3 + 0];
  const float qy = new_xyz[q * 3 + 1];
  const float qz = new_xyz[q * 3 + 2];
  const float* X = xyz + (size_t)b * N_ * 3;
  float lmin = 1e30f;
  int lidx = -1;
  for (int j = 0; j < N_ / 256; ++j) {
    int i = t + j * 256;
    float dx = X[i * 3 + 0] - qx;
    float dy = X[i * 3 + 1] - qy;
    float dz = X[i * 3 + 2] - qz;
    float dsq = fmaf(dx, dx, fmaf(dy, dy, dz * dz));
    sd[i] = dsq;
    if (dsq < lmin) { lmin = dsq; lidx = i; }
  }
  __syncthreads();
  for (int r = 0; r < K_; ++r) {
    float v = lmin;
    int ii = lidx;
#pragma unroll
    for (int off = 32; off > 0; off >>= 1) {
      float ov = __shfl_down(v, off);
      int oi = __shfl_down(ii, off);
      if (ov < v) { v = ov; ii = oi; }
    }
    if ((t & 63) == 0) { s_minv[t >> 6] = v; s_mini[t >> 6] = ii; }
    __syncthreads();
    if (t == 0) {
      float bv = s_minv[0]; int bi = s_mini[0];
#pragma unroll
      for (int w = 1; w < 4; ++w)
        if (s_minv[w] < bv) { bv = s_minv[w]; bi = s_mini[w]; }
      knn_idx[q * K_ + r] = bi;
      s_win = bi;
    }
    __syncthreads();
    int wi = s_win;
    if (wi == lidx) {  // unique owner (disjoint index ranges per thread)
      sd[wi] = 1e30f;
      lmin = 1e30f; lidx = -1;
      for (int j = 0; j < N_ / 256; ++j) {
        int i = t + j * 256;
        float dv = sd[i];
        if (dv < lmin) { lmin = dv; lidx = i; }
      }
    }
  }
}

// ---------------------------------------------------------------------------
// Transpose weights into ws (coalesced per-channel access later) and zero the
// stats region (exactly 49152 elements == transpose work, handled same grid).
// ---------------------------------------------------------------------------
__global__ __launch_bounds__(256) void prep_kernel(const float* __restrict__ W1,
                                                   const float* __restrict__ W2,
                                                   float* __restrict__ W1t,
                                                   float* __restrict__ W2t,
                                                   float* __restrict__ stats) {
  int e = blockIdx.x * 256 + threadIdx.x;  // 0 .. 49151
  stats[e] = 0.0f;
  if (e < C1_ * C0_) {
    int co = e / C0_, c = e % C0_;
    W1t[c * C1_ + co] = W1[e];
  } else {
    int e2 = e - C1_ * C0_;
    int co = e2 / C1_, c = e2 % C1_;
    W2t[c * C2_ + co] = W2[e2];
  }
}

// ---------------------------------------------------------------------------
// conv1 stats: gather + conv1 (y1 pre-BN), accumulate per-channel sum/sumsq.
// Grid 1024 blocks x 8 queries each; slot-sliced atomics (64 slots).
// ---------------------------------------------------------------------------
__global__ __launch_bounds__(256) void conv1_stats_kernel(
    const float* __restrict__ xyz, const float* __restrict__ feat,
    const float* __restrict__ new_xyz, const int* __restrict__ knn,
    const float* __restrict__ W1t, const float* __restrict__ b1,
    float* __restrict__ stats1) {
  __shared__ __align__(16) float sinT[C0_][K_];  // transposed: [c][k]
  __shared__ int sidx[K_];
  __shared__ float sred[256];
  const int t = threadIdx.x;
  float psum = 0.f, psumsq = 0.f;
  const int QPB = (B_ * S_) / 1024;  // 8
  for (int qq = 0; qq < QPB; ++qq) {
    const int q = blockIdx.x * QPB + qq;
    const int b = q / S_;
    if (t < K_) sidx[t] = knn[q * K_ + t];
    __syncthreads();
    const float nx = new_xyz[q * 3 + 0];
    const float ny = new_xyz[q * 3 + 1];
    const float nz = new_xyz[q * 3 + 2];
    for (int e = t; e < K_ * C0_; e += 256) {
      int c = e >> 4, kk = e & 15;
      int i = sidx[kk];
      float v;
      if (c < 3)
        v = xyz[((size_t)b * N_ + i) * 3 + c] - (c == 0 ? nx : (c == 1 ? ny : nz));
      else
        v = feat[((size_t)b * N_ + i) * D_ + (c - 3)];
      sinT[c][kk] = v;
    }
    __syncthreads();
    const int co = t & 127, kh = t >> 7;
    float acc[8];
    float bias = b1[co];
#pragma unroll
    for (int k = 0; k < 8; ++k) acc[k] = bias;
    for (int c = 0; c < C0_; ++c) {
      float w = W1t[c * C1_ + co];
      float4 xa = *(const float4*)&sinT[c][kh * 8];
      float4 xb = *(const float4*)&sinT[c][kh * 8 + 4];
      acc[0] = fmaf(w, xa.x, acc[0]);
      acc[1] = fmaf(w, xa.y, acc[1]);
      acc[2] = fmaf(w, xa.z, acc[2]);
      acc[3] = fmaf(w, xa.w, acc[3]);
      acc[4] = fmaf(w, xb.x, acc[4]);
      acc[5] = fmaf(w, xb.y, acc[5]);
      acc[6] = fmaf(w, xb.z, acc[6]);
      acc[7] = fmaf(w, xb.w, acc[7]);
    }
#pragma unroll
    for (int k = 0; k < 8; ++k) {
      psum += acc[k];
      psumsq = fmaf(acc[k], acc[k], psumsq);
    }
    __syncthreads();
  }
  sred[t] = psum;
  __syncthreads();
  float totsum = (t < 128) ? (sred[t] + sred[t + 128]) : 0.f;
  __syncthreads();
  sred[t] = psumsq;
  __syncthreads();
  if (t < 128) {
    float totsq = sred[t] + sred[t + 128];
    float* st = stats1 + (size_t)(blockIdx.x & (NSLOT - 1)) * (2 * C1_);
    atomicAdd(&st[t], totsum);
    atomicAdd(&st[C1_ + t], totsq);
  }
}

__global__ void finalize1_kernel(const float* __restrict__ stats1,
                                 const float* __restrict__ gamma1,
                                 const float* __restrict__ beta1,
                                 float* __restrict__ ss1) {
  int t = threadIdx.x;  // 128
  float s = 0.f, sq = 0.f;
  for (int w = 0; w < NSLOT; ++w) {
    s += stats1[w * 2 * C1_ + t];
    sq += stats1[w * 2 * C1_ + C1_ + t];
  }
  const float M = (float)(B_ * S_ * K_);
  float m = s / M;
  float v = fmaxf(sq / M - m * m, 0.f);
  float sc = gamma1[t] * rsqrtf(v + 1e-5f);
  ss1[t] = sc;
  ss1[C1_ + t] = fmaf(-m, sc, beta1[t]);
}

// ---------------------------------------------------------------------------
// conv2: re-gather, recompute conv1, apply bn1+relu -> LDS, conv2, per-(q,co2)
// max/min over k, accumulate y2 stats. Grid 1024 x 8 queries.
// ---------------------------------------------------------------------------
__global__ __launch_bounds__(256) void conv2_kernel(
    const float* __restrict__ xyz, const float* __restrict__ feat,
    const float* __restrict__ new_xyz, const int* __restrict__ knn,
    const float* __restrict__ W1t, const float* __restrict__ b1,
    const float* __restrict__ ss1, const float* __restrict__ W2t,
    const float* __restrict__ b2, float* __restrict__ maxv,
    float* __restrict__ minv, float* __restrict__ stats2) {
  __shared__ __align__(16) float sinT[C0_][K_];
  __shared__ __align__(16) float sh1T[C1_][20];  // pad 16->20 (bank spread, 16B-aligned rows)
  __shared__ int sidx[K_];
  const int t = threadIdx.x;
  float psum = 0.f, psumsq = 0.f;
  const int QPB = (B_ * S_) / 1024;  // 8
  for (int qq = 0; qq < QPB; ++qq) {
    const int q = blockIdx.x * QPB + qq;
    const int b = q / S_;
    if (t < K_) sidx[t] = knn[q * K_ + t];
    __syncthreads();
    const float nx = new_xyz[q * 3 + 0];
    const float ny = new_xyz[q * 3 + 1];
    const float nz = new_xyz[q * 3 + 2];
    for (int e = t; e < K_ * C0_; e += 256) {
      int c = e >> 4, kk = e & 15;
      int i = sidx[kk];
      float v;
      if (c < 3)
        v = xyz[((size_t)b * N_ + i) * 3 + c] - (c == 0 ? nx : (c == 1 ? ny : nz));
      else
        v = feat[((size_t)b * N_ + i) * D_ + (c - 3)];
      sinT[c][kk] = v;
    }
    __syncthreads();
    {  // conv1 + bn1 + relu -> sh1T[c_in2][k]
      const int co = t & 127, kh = t >> 7;
      float acc[8];
      float bias = b1[co];
#pragma unroll
      for (int k = 0; k < 8; ++k) acc[k] = bias;
      for (int c = 0; c < C0_; ++c) {
        float w = W1t[c * C1_ + co];
        float4 xa = *(const float4*)&sinT[c][kh * 8];
        float4 xb = *(const float4*)&sinT[c][kh * 8 + 4];
        acc[0] = fmaf(w, xa.x, acc[0]);
        acc[1] = fmaf(w, xa.y, acc[1]);
        acc[2] = fmaf(w, xa.z, acc[2]);
        acc[3] = fmaf(w, xa.w, acc[3]);
        acc[4] = fmaf(w, xb.x, acc[4]);
        acc[5] = fmaf(w, xb.y, acc[5]);
        acc[6] = fmaf(w, xb.z, acc[6]);
        acc[7] = fmaf(w, xb.w, acc[7]);
      }
      float sc = ss1[co], sh = ss1[C1_ + co];
#pragma unroll
      for (int k = 0; k < 8; ++k) {
        float h = fmaxf(fmaf(acc[k], sc, sh), 0.f);
        sh1T[co][kh * 8 + k] = h;
      }
    }
    __syncthreads();
    {  // conv2: thread t -> co2 = t
      float acc2[16];
      float bias2 = b2[t];
#pragma unroll
      for (int k = 0; k < 16; ++k) acc2[k] = bias2;
      for (int c = 0; c < C1_; ++c) {
        float w = W2t[c * C2_ + t];
        float4 h0 = *(const float4*)&sh1T[c][0];
        float4 h1 = *(const float4*)&sh1T[c][4];
        float4 h2 = *(const float4*)&sh1T[c][8];
        float4 h3 = *(const float4*)&sh1T[c][12];
        acc2[0] = fmaf(w, h0.x, acc2[0]);
        acc2[1] = fmaf(w, h0.y, acc2[1]);
        acc2[2] = fmaf(w, h0.z, acc2[2]);
        acc2[3] = fmaf(w, h0.w, acc2[3]);
        acc2[4] = fmaf(w, h1.x, acc2[4]);
        acc2[5] = fmaf(w, h1.y, acc2[5]);
        acc2[6] = fmaf(w, h1.z, acc2[6]);
        acc2[7] = fmaf(w, h1.w, acc2[7]);
        acc2[8] = fmaf(w, h2.x, acc2[8]);
        acc2[9] = fmaf(w, h2.y, acc2[9]);
        acc2[10] = fmaf(w, h2.z, acc2[10]);
        acc2[11] = fmaf(w, h2.w, acc2[11]);
        acc2[12] = fmaf(w, h3.x, acc2[12]);
        acc2[13] = fmaf(w, h3.y, acc2[13]);
        acc2[14] = fmaf(w, h3.z, acc2[14]);
        acc2[15] = fmaf(w, h3.w, acc2[15]);
      }
      float mx = acc2[0], mn = acc2[0];
#pragma unroll
      for (int k = 0; k < 16; ++k) {
        psum += acc2[k];
        psumsq = fmaf(acc2[k], acc2[k], psumsq);
        mx = fmaxf(mx, acc2[k]);
        mn = fminf(mn, acc2[k]);
      }
      maxv[(size_t)q * C2_ + t] = mx;
      minv[(size_t)q * C2_ + t] = mn;
    }
    __syncthreads();
  }
  float* st = stats2 + (size_t)(blockIdx.x & (NSLOT - 1)) * (2 * C2_);
  atomicAdd(&st[t], psum);
  atomicAdd(&st[C2_ + t], psumsq);
}

__global__ void finalize2_kernel(const float* __restrict__ stats2,
                                 const float* __restrict__ gamma2,
                                 const float* __restrict__ beta2,
                                 float* __restrict__ ss2) {
  int t = threadIdx.x;  // 256
  float s = 0.f, sq = 0.f;
  for (int w = 0; w < NSLOT; ++w) {
    s += stats2[w * 2 * C2_ + t];
    sq += stats2[w * 2 * C2_ + C2_ + t];
  }
  const float M = (float)(B_ * S_ * K_);
  float m = s / M;
  float v = fmaxf(sq / M - m * m, 0.f);
  float sc = gamma2[t] * rsqrtf(v + 1e-5f);
  ss2[t] = sc;
  ss2[C2_ + t] = fmaf(-m, sc, beta2[t]);
}

// max_k relu(bn(y)) == relu(bn(max_k y)) for scale>=0 (min_k for scale<0)
__global__ __launch_bounds__(256) void out_kernel(const float* __restrict__ maxv,
                                                  const float* __restrict__ minv,
                                                  const float* __restrict__ ss2,
                                                  float* __restrict__ out2) {
  int e = blockIdx.x * 256 + threadIdx.x;
  int co = e & (C2_ - 1);
  float sc = ss2[co], sh = ss2[C2_ + co];
  float v = (sc >= 0.f) ? maxv[e] : minv[e];
  out2[e] = fmaxf(fmaf(v, sc, sh), 0.f);
}

extern "C" void kernel_launch(void* const* d_in, const int* in_sizes, int n_in,
                              void* d_out, int out_size, void* d_ws, size_t ws_size,
                              hipStream_t stream) {
  (void)in_sizes; (void)n_in; (void)out_size; (void)ws_size;
  const float* xyz = (const float*)d_in[0];
  const float* feat = (const float*)d_in[1];
  const float* W1 = (const float*)d_in[2];
  const float* b1 = (const float*)d_in[3];
  const float* gamma1 = (const float*)d_in[4];
  const float* beta1 = (const float*)d_in[5];
  const float* W2 = (const float*)d_in[6];
  const float* b2 = (const float*)d_in[7];
  const float* gamma2 = (const float*)d_in[8];
  const float* beta2 = (const float*)d_in[9];

  float* out = (float*)d_out;
  float* new_xyz = out;                 // [B,S,3]
  float* out2 = out + B_ * S_ * 3;      // [B,S,C2]

  float* ws = (float*)d_ws;
  float* stats1 = ws;                              // 64*256
  float* stats2 = stats1 + NSLOT * 2 * C1_;        // 64*512
  float* ss1 = stats2 + NSLOT * 2 * C2_;           // 256
  float* ss2 = ss1 + 2 * C1_;                      // 512
  float* W1t = ss2 + 2 * C2_;                      // 16384
  float* W2t = W1t + C1_ * C0_;                    // 32768
  int* knn = (int*)(W2t + (size_t)C2_ * C1_);      // B*S*K ints
  float* maxv = (float*)(knn + B_ * S_ * K_);      // B*S*C2
  float* minv = maxv + (size_t)B_ * S_ * C2_;      // B*S*C2
  // fps sort staging aliases maxv: fps completes (stream-ordered) before
  // conv2_kernel writes maxv, and needs only 3*N*B floats << B*S*C2.
  float* sortbuf = maxv;

  prep_kernel<<<192, 256, 0, stream>>>(W1, W2, W1t, W2t, stats1);
  fps_kernel<<<B_, 512, 0, stream>>>(xyz, new_xyz, sortbuf);
  knn_kernel<<<B_ * S_, 256, 0, stream>>>(xyz, new_xyz, knn);
  conv1_stats_kernel<<<1024, 256, 0, stream>>>(xyz, feat, new_xyz, knn, W1t, b1, stats1);
  finalize1_kernel<<<1, 128, 0, stream>>>(stats1, gamma1, beta1, ss1);
  conv2_kernel<<<1024, 256, 0, stream>>>(xyz, feat, new_xyz, knn, W1t, b1, ss1,
                                         W2t, b2, maxv, minv, stats2);
  finalize2_kernel<<<1, 256, 0, stream>>>(stats2, gamma2, beta2, ss2);
  out_kernel<<<(B_ * S_ * C2_) / 256, 256, 0, stream>>>(maxv, minv, ss2, out2);
}

// Round 10
// 3316.665 us; speedup vs baseline: 1.3191x; 1.3191x over previous
//
#include <hip/hip_runtime.h>

#define B_ 4
#define N_ 16384
#define D_ 125
#define S_ 2048
#define K_ 16
#define C0_ 128
#define C1_ 128
#define C2_ 256
#define NSLOT 64

typedef float v2f __attribute__((ext_vector_type(2)));

// Opaque-ify a float so the compiler cannot rematerialize it from memory.
__device__ __forceinline__ void pin(float& x) { asm volatile("" : "+v"(x)); }

// elementwise max on v2f -> v_pk_max_f32 (exact, order-free)
__device__ __forceinline__ v2f v2max(v2f a, v2f b) {
  v2f r;
  r.x = fmaxf(a.x, b.x);
  r.y = fmaxf(a.y, b.y);
  return r;
}

// ---------------------------------------------------------------------------
// 64-bit max/min reduction step via DPP (pure VALU, no ds_bpermute).
// Keys are positive finite doubles -> fmax/fmin == u64 max/min. old=own
// word + bound_ctrl=false => masked lanes yield own value (identity).
// After row_shr 1/2/4/8 + row_bcast15(0xa) + row_bcast31(0xc), lane 63
// holds the wave max/min. (HW-verified R5/R6/R8)
// ---------------------------------------------------------------------------
template <int CTRL, int RMASK>
__device__ __forceinline__ double dppmax(double k) {
  const long long kb = __double_as_longlong(k);
  const int lo = (int)(kb & 0xffffffffll);
  const int hi = (int)(((unsigned long long)kb) >> 32);
  const int plo = __builtin_amdgcn_update_dpp(lo, lo, CTRL, RMASK, 0xf, false);
  const int phi = __builtin_amdgcn_update_dpp(hi, hi, CTRL, RMASK, 0xf, false);
  const double p =
      __longlong_as_double(((long long)phi << 32) | (unsigned int)plo);
  return fmax(k, p);
}
template <int CTRL, int RMASK>
__device__ __forceinline__ double dppmin(double k) {
  const long long kb = __double_as_longlong(k);
  const int lo = (int)(kb & 0xffffffffll);
  const int hi = (int)(((unsigned long long)kb) >> 32);
  const int plo = __builtin_amdgcn_update_dpp(lo, lo, CTRL, RMASK, 0xf, false);
  const int phi = __builtin_amdgcn_update_dpp(hi, hi, CTRL, RMASK, 0xf, false);
  const double p =
      __longlong_as_double(((long long)phi << 32) | (unsigned int)plo);
  return fmin(k, p);
}

// ---------------------------------------------------------------------------
// FPS v8 (R8-verified, 2507us): one block per batch, 1024 threads, 16
// points/thread. Morton counting sort (16^3) once at start; per-thread bbox
// gives an exact lower bound L (same rounding shape as the distance,
// L <= fl(dist^2)) so a wave whose lanes all satisfy L >= tmax skips the
// whole update. Single barrier; tagged ds_max_u64 publish
//   key = (s<<52)|(f32bits<<20)|(inv<<4)|wave_id
// dbuf key + per-wave coords slots, f64-punned DPP wave reduce, max3 box
// test, pk_max lane tree, setprio around the active branch.
// R9 lesson: 512thr/32pt variant is latency-starved (-40%); 1024/16 is the
// measured optimum of this structure. fps closed; do not touch.
// ---------------------------------------------------------------------------
__global__ __attribute__((amdgpu_flat_work_group_size(1024, 1024),
                          amdgpu_waves_per_eu(4, 4)))
void fps_kernel(const float* __restrict__ xyz, float* __restrict__ new_xyz,
                float* __restrict__ sortbuf) {
#pragma clang fp contract(off)
  const int b = blockIdx.x;
  const float* X = xyz + (size_t)b * N_ * 3;
  float* SB = sortbuf + (size_t)b * 3 * N_;
  const int t = threadIdx.x;
  constexpr int PAIRS = N_ / 1024 / 2;  // 8 pairs = 16 points/thread
  const int base = t * (2 * PAIRS);     // orig-load base AND sorted slot base

  __shared__ unsigned int s_hist[4096];          // 16 KB (sort only)
  __shared__ float s_bb[16][8];                  // wave bboxes (sort only)
  __shared__ unsigned int s_wsum[16];            // scan wave totals
  __shared__ unsigned short s_sidx[N_];          // 32 KB: slot -> orig index
  __shared__ unsigned long long s_k1[2];         // dbuf block-winner key
  __shared__ __align__(16) float4 s_cc[2][16];   // per-wave candidate coords

  // ---- load my 16 original points: 12 x float4 = 48 contiguous floats ----
  float arr[48];
  {
    float4* a4 = (float4*)arr;
#pragma unroll
    for (int i = 0; i < 12; ++i) a4[i] = *(const float4*)(X + base * 3 + 4 * i);
  }
  // ---- block bbox ----
  float lx0 = arr[0], lx1 = arr[0], ly0 = arr[1], ly1 = arr[1];
  float lz0 = arr[2], lz1 = arr[2];
#pragma unroll
  for (int p = 1; p < 16; ++p) {
    lx0 = fminf(lx0, arr[3 * p + 0]); lx1 = fmaxf(lx1, arr[3 * p + 0]);
    ly0 = fminf(ly0, arr[3 * p + 1]); ly1 = fmaxf(ly1, arr[3 * p + 1]);
    lz0 = fminf(lz0, arr[3 * p + 2]); lz1 = fmaxf(lz1, arr[3 * p + 2]);
  }
#pragma unroll
  for (int off = 32; off > 0; off >>= 1) {
    lx0 = fminf(lx0, __shfl_xor(lx0, off)); lx1 = fmaxf(lx1, __shfl_xor(lx1, off));
    ly0 = fminf(ly0, __shfl_xor(ly0, off)); ly1 = fmaxf(ly1, __shfl_xor(ly1, off));
    lz0 = fminf(lz0, __shfl_xor(lz0, off)); lz1 = fmaxf(lz1, __shfl_xor(lz1, off));
  }
  if ((t & 63) == 0) {
    const int w = t >> 6;
    s_bb[w][0] = lx0; s_bb[w][1] = lx1; s_bb[w][2] = ly0;
    s_bb[w][3] = ly1; s_bb[w][4] = lz0; s_bb[w][5] = lz1;
  }
  for (int i = t; i < 4096; i += 1024) s_hist[i] = 0u;
  if (t == 0) { s_k1[0] = 0ull; s_k1[1] = 0ull; }
  __syncthreads();
  float gx0 = s_bb[0][0], gx1 = s_bb[0][1], gy0 = s_bb[0][2];
  float gy1 = s_bb[0][3], gz0 = s_bb[0][4], gz1 = s_bb[0][5];
#pragma unroll
  for (int w = 1; w < 16; ++w) {
    gx0 = fminf(gx0, s_bb[w][0]); gx1 = fmaxf(gx1, s_bb[w][1]);
    gy0 = fminf(gy0, s_bb[w][2]); gy1 = fmaxf(gy1, s_bb[w][3]);
    gz0 = fminf(gz0, s_bb[w][4]); gz1 = fmaxf(gz1, s_bb[w][5]);
  }
  const float ivx = (gx1 > gx0) ? 16.0f / (gx1 - gx0) : 0.0f;
  const float ivy = (gy1 > gy0) ? 16.0f / (gy1 - gy0) : 0.0f;
  const float ivz = (gz1 > gz0) ? 16.0f / (gz1 - gz0) : 0.0f;
  // ---- Morton cell per point + histogram ----
  int cell[16];
#pragma unroll
  for (int p = 0; p < 16; ++p) {
    int qx = min(15, (int)((arr[3 * p + 0] - gx0) * ivx));
    int qy = min(15, (int)((arr[3 * p + 1] - gy0) * ivy));
    int qz = min(15, (int)((arr[3 * p + 2] - gz0) * ivz));
    int mx = (qx & 1) | ((qx & 2) << 2) | ((qx & 4) << 4) | ((qx & 8) << 6);
    int my = (qy & 1) | ((qy & 2) << 2) | ((qy & 4) << 4) | ((qy & 8) << 6);
    int mz = (qz & 1) | ((qz & 2) << 2) | ((qz & 4) << 4) | ((qz & 8) << 6);
    cell[p] = mx | (my << 1) | (mz << 2);
    atomicAdd(&s_hist[cell[p]], 1u);
  }
  __syncthreads();
  // ---- exclusive scan of 4096 bins (4 per thread, thread-major = bin order)
  {
    unsigned int c0 = s_hist[4 * t + 0], c1 = s_hist[4 * t + 1];
    unsigned int c2 = s_hist[4 * t + 2], c3 = s_hist[4 * t + 3];
    (void)c3;
    unsigned int tsum = c0 + c1 + c2 + c3;
    unsigned int incl = tsum;
#pragma unroll
    for (int off = 1; off < 64; off <<= 1) {
      unsigned int nv = __shfl_up(incl, off);
      if ((t & 63) >= off) incl += nv;
    }
    if ((t & 63) == 63) s_wsum[t >> 6] = incl;
    __syncthreads();
    unsigned int wpre = 0;
    const int myw = t >> 6;
    for (int w = 0; w < myw; ++w) wpre += s_wsum[w];
    const unsigned int texc = wpre + incl - tsum;
    s_hist[4 * t + 0] = texc;
    s_hist[4 * t + 1] = texc + c0;
    s_hist[4 * t + 2] = texc + c0 + c1;
    s_hist[4 * t + 3] = texc + c0 + c1 + c2;
  }
  __syncthreads();
  // ---- scatter points + orig indices ----
#pragma unroll
  for (int p = 0; p < 16; ++p) {
    const unsigned int slot = atomicAdd(&s_hist[cell[p]], 1u);
    SB[slot]          = arr[3 * p + 0];
    SB[N_ + slot]     = arr[3 * p + 1];
    SB[2 * N_ + slot] = arr[3 * p + 2];
    s_sidx[slot] = (unsigned short)(base + p);
  }
  __threadfence();
  __syncthreads();
  __threadfence();

  // ---- reload sorted points (coalesced float4) ----
  v2f px[PAIRS], py[PAIRS], pz[PAIRS], d[PAIRS];
  {
    float4 xa[4], ya[4], za[4];
#pragma unroll
    for (int i = 0; i < 4; ++i) {
      xa[i] = *(const float4*)(SB + base + 4 * i);
      ya[i] = *(const float4*)(SB + N_ + base + 4 * i);
      za[i] = *(const float4*)(SB + 2 * N_ + base + 4 * i);
    }
    const float* xf = (const float*)xa;
    const float* yf = (const float*)ya;
    const float* zf = (const float*)za;
#pragma unroll
    for (int j = 0; j < PAIRS; ++j) {
      px[j] = (v2f){xf[2 * j], xf[2 * j + 1]};
      py[j] = (v2f){yf[2 * j], yf[2 * j + 1]};
      pz[j] = (v2f){zf[2 * j], zf[2 * j + 1]};
      d[j] = (v2f){1e10f, 1e10f};
    }
  }
  // inverted original indices, u16-packed: ~word == (0xFFFF-hi, 0xFFFF-lo)
  // orig < 16384 so inv in [0xC000, 0xFFFF] and is globally unique.
  unsigned int invw[PAIRS];
  {
    const unsigned int* SI = (const unsigned int*)&s_sidx[base];
#pragma unroll
    for (int j = 0; j < PAIRS; ++j) invw[j] = ~SI[j];
  }
  // per-thread bbox of my (now spatially-coherent) 16 points
  float bx0 = 1e30f, bx1 = -1e30f, by0 = 1e30f, by1 = -1e30f;
  float bz0 = 1e30f, bz1 = -1e30f;
#pragma unroll
  for (int j = 0; j < PAIRS; ++j) {
    bx0 = fminf(bx0, fminf(px[j].x, px[j].y));
    bx1 = fmaxf(bx1, fmaxf(px[j].x, px[j].y));
    by0 = fminf(by0, fminf(py[j].x, py[j].y));
    by1 = fmaxf(by1, fmaxf(py[j].x, py[j].y));
    bz0 = fminf(bz0, fminf(pz[j].x, pz[j].y));
    bz1 = fmaxf(bz1, fmaxf(pz[j].x, pz[j].y));
  }
  // Pin coordinates into registers (blocks rematerialization from memory).
#pragma unroll
  for (int j = 0; j < PAIRS; ++j) {
    float a0 = px[j].x, a1 = px[j].y;
    float b0 = py[j].x, b1 = py[j].y;
    float c0 = pz[j].x, c1 = pz[j].y;
    pin(a0); pin(a1); pin(b0); pin(b1); pin(c0); pin(c1);
    px[j] = (v2f){a0, a1};
    py[j] = (v2f){b0, b1};
    pz[j] = (v2f){c0, c1};
  }
  float cx = X[0], cy = X[1], cz = X[2];  // centroid 0 (orig point 0)
  float tmax = 1e10f;                     // exact max of this lane's d[]
  unsigned long long keylow = 0ull;       // cached wave-winner low-52 key
  bool iwin = false;                      // am I my wave's winner lane?
  float ccx = 0.f, ccy = 0.f, ccz = 0.f;  // cached lane candidate coords
  float cap_x = 0.f, cap_y = 0.f, cap_z = 0.f;
  const unsigned int wid = (unsigned int)(t >> 6);
  for (int s = 0; s < S_; ++s) {
    if (((s - t) & 1023) == 0) { cap_x = cx; cap_y = cy; cap_z = cz; }
    if ((s & 1023) == 1023) {  // epoch flush: 1024 coalesced centroids
      const int o = (b * S_ + (s & ~1023) + t) * 3;
      new_xyz[o + 0] = cap_x;
      new_xyz[o + 1] = cap_y;
      new_xyz[o + 2] = cap_z;
    }
    if (s == S_ - 1) break;  // last index needs no further update
    const int buf = s & 1;
    // ---- exact box lower bound, same rounding shape as the distance ----
    const float mx = fmaxf(fmaxf(bx0 - cx, cx - bx1), 0.0f);
    const float my = fmaxf(fmaxf(by0 - cy, cy - by1), 0.0f);
    const float mz = fmaxf(fmaxf(bz0 - cz, cz - bz1), 0.0f);
    const float L = (mx * mx + my * my) + mz * mz;  // L <= fl(dist^2) for all
    if (__any(L < tmax)) {
      __builtin_amdgcn_s_setprio(1);  // favor the critical active wave (T5)
      // ---- value update (packed, register-resident; no in-loop max) ----
      const v2f c2x = {cx, cx}, c2y = {cy, cy}, c2z = {cz, cz};
#pragma unroll
      for (int j = 0; j < PAIRS; ++j) {
        v2f dx = px[j] - c2x;
        v2f dy = py[j] - c2y;
        v2f dz = pz[j] - c2z;
        v2f sq = (dx * dx + dy * dy) + dz * dz;  // exact ref order
        v2f dm;
        dm.x = fminf(d[j].x, sq.x);
        dm.y = fminf(d[j].y, sq.y);
        d[j] = dm;
      }
      // ---- lane max via pk_max tree (max exact & order-free) ----
      const v2f m01 = v2max(d[0], d[1]);
      const v2f m23 = v2max(d[2], d[3]);
      const v2f m45 = v2max(d[4], d[5]);
      const v2f m67 = v2max(d[6], d[7]);
      const v2f m03 = v2max(m01, m23);
      const v2f m47 = v2max(m45, m67);
      const v2f m07 = v2max(m03, m47);
      const float lmax = fmaxf(m07.x, m07.y);
      tmax = lmax;
      // ---- lane tie-break in registers: max inv == min orig idx ----
      unsigned int binv = 0u;
#pragma unroll
      for (int j = 0; j < PAIRS; ++j) {
        const unsigned int lo = invw[j] & 0xFFFFu;
        const unsigned int hi = invw[j] >> 16;
        if (d[j].x == lmax) binv = max(binv, lo);
        if (d[j].y == lmax) binv = max(binv, hi);
      }
      // ---- lane candidate coords (unique inv match) ----
#pragma unroll
      for (int j = 0; j < PAIRS; ++j) {
        const unsigned int lo = invw[j] & 0xFFFFu;
        const unsigned int hi = invw[j] >> 16;
        if (lo == binv) { ccx = px[j].x; ccy = py[j].x; ccz = pz[j].x; }
        if (hi == binv) { ccx = px[j].y; ccy = py[j].y; ccz = pz[j].y; }
      }
      // ---- low-52 key; DPP max reduce (pure VALU, active waves only) ----
      const unsigned long long k52 =
          ((unsigned long long)__float_as_uint(lmax) << 20) |
          (unsigned long long)((binv << 4) | wid);
      double dk = __longlong_as_double((long long)k52);
      dk = dppmax<0x111, 0xf>(dk);  // row_shr:1
      dk = dppmax<0x112, 0xf>(dk);  // row_shr:2
      dk = dppmax<0x114, 0xf>(dk);  // row_shr:4
      dk = dppmax<0x118, 0xf>(dk);  // row_shr:8 -> lane15+16r = row max
      dk = dppmax<0x142, 0xa>(dk);  // row_bcast15 rows 1,3
      dk = dppmax<0x143, 0xc>(dk);  // row_bcast31 rows 2,3 -> lane63 = wave max
      const long long kb = __double_as_longlong(dk);
      const int rlo = __builtin_amdgcn_readlane((int)(kb & 0xffffffffll), 63);
      const int rhi =
          __builtin_amdgcn_readlane((int)(((unsigned long long)kb) >> 32), 63);
      const unsigned long long wk52 =
          ((unsigned long long)(unsigned int)rhi << 32) | (unsigned int)rlo;
      iwin = (k52 == wk52);
      keylow = wk52;
      __builtin_amdgcn_s_setprio(0);
    }
    // ---- winner lane publishes tagged key + coords (O(1) per wave) ----
    // skipped wave: candidate provably unchanged; re-tag cached keylow.
    if (iwin) {
      atomicMax(&s_k1[buf], ((unsigned long long)s << 52) | keylow);
      s_cc[buf][wid] = make_float4(ccx, ccy, ccz, 0.f);
    }
    __syncthreads();
    // ---- block winner: one uniform b64 read + one uniform b128 read ----
    const unsigned long long bk = s_k1[buf];
    const int w_win = (int)(bk & 15ull);
    const float4 cc = s_cc[buf][w_win];
    cx = cc.x; cy = cc.y; cz = cc.z;
  }
}

// ---------------------------------------------------------------------------
// kNN v2: one block (256 thr) per query; distances in LDS; 16 rounds of
// block-min. R10: fps-proven machinery ported to min: per-wave f64-punned
// DPP v_min_f64 reduce (replaces 12 dependent ds_bpermute, ~700cy -> ~100cy)
// and ONE tagged ds_min_u64 per wave into a dbuf slot (replaces 2nd barrier
// + t0 serial scan). Key = ((7-(r>>1))<<60)|(dist_bits<<28)|idx: tag <= 7
// keeps the double positive-finite (fmin == u64 min); strictly-decreasing
// tag per slot makes stale round-(r-2) entries lose automatically; slot
// read/write intervals are barrier-separated (R6-verified scheme).
// Tie-break = min index on equal distance (continuous data; result consumed
// as a set). Winner-only local rescan unchanged (disjoint ownership).
// ---------------------------------------------------------------------------
__global__ __launch_bounds__(256) void knn_kernel(const float* __restrict__ xyz,
                                                  const float* __restrict__ new_xyz,
                                                  int* __restrict__ knn_idx) {
  const int q = blockIdx.x;  // b*S + s
  const int b = q / S_;
  __shared__ float sd[N_];  // 64 KB
  __shared__ unsigned long long s_kd[2];  // dbuf round-winner key
  const int t = threadIdx.x;
  if (t == 0) { s_kd[0] = ~0ull; s_kd[1] = ~0ull; }  // integer-max: loses
  const float qx = new_xyz[q * 3 + 0];
  const float qy = new_xyz[q * 3 + 1];
  const float qz = new_xyz[q * 3 + 2];
  const float* X = xyz + (size_t)b * N_ * 3;
  float lmin = 1e30f;
  int lidx = -1;
  for (int j = 0; j < N_ / 256; ++j) {
    int i = t + j * 256;
    float dx = X[i * 3 + 0] - qx;
    float dy = X[i * 3 + 1] - qy;
    float dz = X[i * 3 + 2] - qz;
    float dsq = fmaf(dx, dx, fmaf(dy, dy, dz * dz));
    sd[i] = dsq;
    if (dsq < lmin) { lmin = dsq; lidx = i; }
  }
  __syncthreads();
  for (int r = 0; r < K_; ++r) {
    // ---- pack (tag, dist, idx); positive finite double ----
    const unsigned long long k =
        ((unsigned long long)(7 - (r >> 1)) << 60) |
        ((unsigned long long)__float_as_uint(lmin) << 28) |
        (unsigned int)(lidx & 0x0FFFFFFF);
    // ---- wave min via DPP (pure VALU) ----
    double dk = __longlong_as_double((long long)k);
    dk = dppmin<0x111, 0xf>(dk);  // row_shr:1
    dk = dppmin<0x112, 0xf>(dk);  // row_shr:2
    dk = dppmin<0x114, 0xf>(dk);  // row_shr:4
    dk = dppmin<0x118, 0xf>(dk);  // row_shr:8
    dk = dppmin<0x142, 0xa>(dk);  // row_bcast15
    dk = dppmin<0x143, 0xc>(dk);  // row_bcast31 -> lane63 = wave min
    const long long kb = __double_as_longlong(dk);
    const int rlo = __builtin_amdgcn_readlane((int)(kb & 0xffffffffll), 63);
    const int rhi =
        __builtin_amdgcn_readlane((int)(((unsigned long long)kb) >> 32), 63);
    const unsigned long long wk =
        ((unsigned long long)(unsigned int)rhi << 32) | (unsigned int)rlo;
    if ((t & 63) == 0) atomicMin(&s_kd[r & 1], wk);
    __syncthreads();
    const unsigned long long bk = s_kd[r & 1];
    const int wi = (int)(bk & 0x0FFFFFFFull);
    if (t == 0) knn_idx[q * K_ + r] = wi;
    if (wi == lidx) {  // unique owner (disjoint index ranges per thread)
      sd[wi] = 1e30f;
      lmin = 1e30f; lidx = -1;
      for (int j = 0; j < N_ / 256; ++j) {
        int i = t + j * 256;
        float dv = sd[i];
        if (dv < lmin) { lmin = dv; lidx = i; }
      }
    }
  }
}

// ---------------------------------------------------------------------------
// Transpose weights into ws (coalesced per-channel access later) and zero the
// stats region (exactly 49152 elements == transpose work, handled same grid).
// ---------------------------------------------------------------------------
__global__ __launch_bounds__(256) void prep_kernel(const float* __restrict__ W1,
                                                   const float* __restrict__ W2,
                                                   float* __restrict__ W1t,
                                                   float* __restrict__ W2t,
                                                   float* __restrict__ stats) {
  int e = blockIdx.x * 256 + threadIdx.x;  // 0 .. 49151
  stats[e] = 0.0f;
  if (e < C1_ * C0_) {
    int co = e / C0_, c = e % C0_;
    W1t[c * C1_ + co] = W1[e];
  } else {
    int e2 = e - C1_ * C0_;
    int co = e2 / C1_, c = e2 % C1_;
    W2t[c * C2_ + co] = W2[e2];
  }
}

// ---------------------------------------------------------------------------
// conv1 stats: gather + conv1 (y1 pre-BN), accumulate per-channel sum/sumsq.
// Grid 1024 blocks x 8 queries each; slot-sliced atomics (64 slots).
// ---------------------------------------------------------------------------
__global__ __launch_bounds__(256) void conv1_stats_kernel(
    const float* __restrict__ xyz, const float* __restrict__ feat,
    const float* __restrict__ new_xyz, const int* __restrict__ knn,
    const float* __restrict__ W1t, const float* __restrict__ b1,
    float* __restrict__ stats1) {
  __shared__ __align__(16) float sinT[C0_][K_];  // transposed: [c][k]
  __shared__ int sidx[K_];
  __shared__ float sred[256];
  const int t = threadIdx.x;
  float psum = 0.f, psumsq = 0.f;
  const int QPB = (B_ * S_) / 1024;  // 8
  for (int qq = 0; qq < QPB; ++qq) {
    const int q = blockIdx.x * QPB + qq;
    const int b = q / S_;
    if (t < K_) sidx[t] = knn[q * K_ + t];
    __syncthreads();
    const float nx = new_xyz[q * 3 + 0];
    const float ny = new_xyz[q * 3 + 1];
    const float nz = new_xyz[q * 3 + 2];
    for (int e = t; e < K_ * C0_; e += 256) {
      int c = e >> 4, kk = e & 15;
      int i = sidx[kk];
      float v;
      if (c < 3)
        v = xyz[((size_t)b * N_ + i) * 3 + c] - (c == 0 ? nx : (c == 1 ? ny : nz));
      else
        v = feat[((size_t)b * N_ + i) * D_ + (c - 3)];
      sinT[c][kk] = v;
    }
    __syncthreads();
    const int co = t & 127, kh = t >> 7;
    float acc[8];
    float bias = b1[co];
#pragma unroll
    for (int k = 0; k < 8; ++k) acc[k] = bias;
    for (int c = 0; c < C0_; ++c) {
      float w = W1t[c * C1_ + co];
      float4 xa = *(const float4*)&sinT[c][kh * 8];
      float4 xb = *(const float4*)&sinT[c][kh * 8 + 4];
      acc[0] = fmaf(w, xa.x, acc[0]);
      acc[1] = fmaf(w, xa.y, acc[1]);
      acc[2] = fmaf(w, xa.z, acc[2]);
      acc[3] = fmaf(w, xa.w, acc[3]);
      acc[4] = fmaf(w, xb.x, acc[4]);
      acc[5] = fmaf(w, xb.y, acc[5]);
      acc[6] = fmaf(w, xb.z, acc[6]);
      acc[7] = fmaf(w, xb.w, acc[7]);
    }
#pragma unroll
    for (int k = 0; k < 8; ++k) {
      psum += acc[k];
      psumsq = fmaf(acc[k], acc[k], psumsq);
    }
    __syncthreads();
  }
  sred[t] = psum;
  __syncthreads();
  float totsum = (t < 128) ? (sred[t] + sred[t + 128]) : 0.f;
  __syncthreads();
  sred[t] = psumsq;
  __syncthreads();
  if (t < 128) {
    float totsq = sred[t] + sred[t + 128];
    float* st = stats1 + (size_t)(blockIdx.x & (NSLOT - 1)) * (2 * C1_);
    atomicAdd(&st[t], totsum);
    atomicAdd(&st[C1_ + t], totsq);
  }
}

__global__ void finalize1_kernel(const float* __restrict__ stats1,
                                 const float* __restrict__ gamma1,
                                 const float* __restrict__ beta1,
                                 float* __restrict__ ss1) {
  int t = threadIdx.x;  // 128
  float s = 0.f, sq = 0.f;
  for (int w = 0; w < NSLOT; ++w) {
    s += stats1[w * 2 * C1_ + t];
    sq += stats1[w * 2 * C1_ + C1_ + t];
  }
  const float M = (float)(B_ * S_ * K_);
  float m = s / M;
  float v = fmaxf(sq / M - m * m, 0.f);
  float sc = gamma1[t] * rsqrtf(v + 1e-5f);
  ss1[t] = sc;
  ss1[C1_ + t] = fmaf(-m, sc, beta1[t]);
}

// ---------------------------------------------------------------------------
// conv2: re-gather, recompute conv1, apply bn1+relu -> LDS, conv2, per-(q,co2)
// max/min over k, accumulate y2 stats. Grid 1024 x 8 queries.
// ---------------------------------------------------------------------------
__global__ __launch_bounds__(256) void conv2_kernel(
    const float* __restrict__ xyz, const float* __restrict__ feat,
    const float* __restrict__ new_xyz, const int* __restrict__ knn,
    const float* __restrict__ W1t, const float* __restrict__ b1,
    const float* __restrict__ ss1, const float* __restrict__ W2t,
    const float* __restrict__ b2, float* __restrict__ maxv,
    float* __restrict__ minv, float* __restrict__ stats2) {
  __shared__ __align__(16) float sinT[C0_][K_];
  __shared__ __align__(16) float sh1T[C1_][20];  // pad 16->20 (bank spread, 16B-aligned rows)
  __shared__ int sidx[K_];
  const int t = threadIdx.x;
  float psum = 0.f, psumsq = 0.f;
  const int QPB = (B_ * S_) / 1024;  // 8
  for (int qq = 0; qq < QPB; ++qq) {
    const int q = blockIdx.x * QPB + qq;
    const int b = q / S_;
    if (t < K_) sidx[t] = knn[q * K_ + t];
    __syncthreads();
    const float nx = new_xyz[q * 3 + 0];
    const float ny = new_xyz[q * 3 + 1];
    const float nz = new_xyz[q * 3 + 2];
    for (int e = t; e < K_ * C0_; e += 256) {
      int c = e >> 4, kk = e & 15;
      int i = sidx[kk];
      float v;
      if (c < 3)
        v = xyz[((size_t)b * N_ + i) * 3 + c] - (c == 0 ? nx : (c == 1 ? ny : nz));
      else
        v = feat[((size_t)b * N_ + i) * D_ + (c - 3)];
      sinT[c][kk] = v;
    }
    __syncthreads();
    {  // conv1 + bn1 + relu -> sh1T[c_in2][k]
      const int co = t & 127, kh = t >> 7;
      float acc[8];
      float bias = b1[co];
#pragma unroll
      for (int k = 0; k < 8; ++k) acc[k] = bias;
      for (int c = 0; c < C0_; ++c) {
        float w = W1t[c * C1_ + co];
        float4 xa = *(const float4*)&sinT[c][kh * 8];
        float4 xb = *(const float4*)&sinT[c][kh * 8 + 4];
        acc[0] = fmaf(w, xa.x, acc[0]);
        acc[1] = fmaf(w, xa.y, acc[1]);
        acc[2] = fmaf(w, xa.z, acc[2]);
        acc[3] = fmaf(w, xa.w, acc[3]);
        acc[4] = fmaf(w, xb.x, acc[4]);
        acc[5] = fmaf(w, xb.y, acc[5]);
        acc[6] = fmaf(w, xb.z, acc[6]);
        acc[7] = fmaf(w, xb.w, acc[7]);
      }
      float sc = ss1[co], sh = ss1[C1_ + co];
#pragma unroll
      for (int k = 0; k < 8; ++k) {
        float h = fmaxf(fmaf(acc[k], sc, sh), 0.f);
        sh1T[co][kh * 8 + k] = h;
      }
    }
    __syncthreads();
    {  // conv2: thread t -> co2 = t
      float acc2[16];
      float bias2 = b2[t];
#pragma unroll
      for (int k = 0; k < 16; ++k) acc2[k] = bias2;
      for (int c = 0; c < C1_; ++c) {
        float w = W2t[c * C2_ + t];
        float4 h0 = *(const float4*)&sh1T[c][0];
        float4 h1 = *(const float4*)&sh1T[c][4];
        float4 h2 = *(const float4*)&sh1T[c][8];
        float4 h3 = *(const float4*)&sh1T[c][12];
        acc2[0] = fmaf(w, h0.x, acc2[0]);
        acc2[1] = fmaf(w, h0.y, acc2[1]);
        acc2[2] = fmaf(w, h0.z, acc2[2]);
        acc2[3] = fmaf(w, h0.w, acc2[3]);
        acc2[4] = fmaf(w, h1.x, acc2[4]);
        acc2[5] = fmaf(w, h1.y, acc2[5]);
        acc2[6] = fmaf(w, h1.z, acc2[6]);
        acc2[7] = fmaf(w, h1.w, acc2[7]);
        acc2[8] = fmaf(w, h2.x, acc2[8]);
        acc2[9] = fmaf(w, h2.y, acc2[9]);
        acc2[10] = fmaf(w, h2.z, acc2[10]);
        acc2[11] = fmaf(w, h2.w, acc2[11]);
        acc2[12] = fmaf(w, h3.x, acc2[12]);
        acc2[13] = fmaf(w, h3.y, acc2[13]);
        acc2[14] = fmaf(w, h3.z, acc2[14]);
        acc2[15] = fmaf(w, h3.w, acc2[15]);
      }
      float mx = acc2[0], mn = acc2[0];
#pragma unroll
      for (int k = 0; k < 16; ++k) {
        psum += acc2[k];
        psumsq = fmaf(acc2[k], acc2[k], psumsq);
        mx = fmaxf(mx, acc2[k]);
        mn = fminf(mn, acc2[k]);
      }
      maxv[(size_t)q * C2_ + t] = mx;
      minv[(size_t)q * C2_ + t] = mn;
    }
    __syncthreads();
  }
  float* st = stats2 + (size_t)(blockIdx.x & (NSLOT - 1)) * (2 * C2_);
  atomicAdd(&st[t], psum);
  atomicAdd(&st[C2_ + t], psumsq);
}

__global__ void finalize2_kernel(const float* __restrict__ stats2,
                                 const float* __restrict__ gamma2,
                                 const float* __restrict__ beta2,
                                 float* __restrict__ ss2) {
  int t = threadIdx.x;  // 256
  float s = 0.f, sq = 0.f;
  for (int w = 0; w < NSLOT; ++w) {
    s += stats2[w * 2 * C2_ + t];
    sq += stats2[w * 2 * C2_ + C2_ + t];
  }
  const float M = (float)(B_ * S_ * K_);
  float m = s / M;
  float v = fmaxf(sq / M - m * m, 0.f);
  float sc = gamma2[t] * rsqrtf(v + 1e-5f);
  ss2[t] = sc;
  ss2[C2_ + t] = fmaf(-m, sc, beta2[t]);
}

// max_k relu(bn(y)) == relu(bn(max_k y)) for scale>=0 (min_k for scale<0)
__global__ __launch_bounds__(256) void out_kernel(const float* __restrict__ maxv,
                                                  const float* __restrict__ minv,
                                                  const float* __restrict__ ss2,
                                                  float* __restrict__ out2) {
  int e = blockIdx.x * 256 + threadIdx.x;
  int co = e & (C2_ - 1);
  float sc = ss2[co], sh = ss2[C2_ + co];
  float v = (sc >= 0.f) ? maxv[e] : minv[e];
  out2[e] = fmaxf(fmaf(v, sc, sh), 0.f);
}

extern "C" void kernel_launch(void* const* d_in, const int* in_sizes, int n_in,
                              void* d_out, int out_size, void* d_ws, size_t ws_size,
                              hipStream_t stream) {
  (void)in_sizes; (void)n_in; (void)out_size; (void)ws_size;
  const float* xyz = (const float*)d_in[0];
  const float* feat = (const float*)d_in[1];
  const float* W1 = (const float*)d_in[2];
  const float* b1 = (const float*)d_in[3];
  const float* gamma1 = (const float*)d_in[4];
  const float* beta1 = (const float*)d_in[5];
  const float* W2 = (const float*)d_in[6];
  const float* b2 = (const float*)d_in[7];
  const float* gamma2 = (const float*)d_in[8];
  const float* beta2 = (const float*)d_in[9];

  float* out = (float*)d_out;
  float* new_xyz = out;                 // [B,S,3]
  float* out2 = out + B_ * S_ * 3;      // [B,S,C2]

  float* ws = (float*)d_ws;
  float* stats1 = ws;                              // 64*256
  float* stats2 = stats1 + NSLOT * 2 * C1_;        // 64*512
  float* ss1 = stats2 + NSLOT * 2 * C2_;           // 256
  float* ss2 = ss1 + 2 * C1_;                      // 512
  float* W1t = ss2 + 2 * C2_;                      // 16384
  float* W2t = W1t + C1_ * C0_;                    // 32768
  int* knn = (int*)(W2t + (size_t)C2_ * C1_);      // B*S*K ints
  float* maxv = (float*)(knn + B_ * S_ * K_);      // B*S*C2
  float* minv = maxv + (size_t)B_ * S_ * C2_;      // B*S*C2
  // fps sort staging aliases maxv: fps completes (stream-ordered) before
  // conv2_kernel writes maxv, and needs only 3*N*B floats << B*S*C2.
  float* sortbuf = maxv;

  prep_kernel<<<192, 256, 0, stream>>>(W1, W2, W1t, W2t, stats1);
  fps_kernel<<<B_, 1024, 0, stream>>>(xyz, new_xyz, sortbuf);
  knn_kernel<<<B_ * S_, 256, 0, stream>>>(xyz, new_xyz, knn);
  conv1_stats_kernel<<<1024, 256, 0, stream>>>(xyz, feat, new_xyz, knn, W1t, b1, stats1);
  finalize1_kernel<<<1, 128, 0, stream>>>(stats1, gamma1, beta1, ss1);
  conv2_kernel<<<1024, 256, 0, stream>>>(xyz, feat, new_xyz, knn, W1t, b1, ss1,
                                         W2t, b2, maxv, minv, stats2);
  finalize2_kernel<<<1, 256, 0, stream>>>(stats2, gamma2, beta2, ss2);
  out_kernel<<<(B_ * S_ * C2_) / 256, 256, 0, stream>>>(maxv, minv, ss2, out2);
}

// Round 12
// 3166.169 us; speedup vs baseline: 1.3818x; 1.0475x over previous
//
#include <hip/hip_runtime.h>

#define B_ 4
#define N_ 16384
#define D_ 125
#define S_ 2048
#define K_ 16
#define C0_ 128
#define C1_ 128
#define C2_ 256
#define NSLOT 64

typedef float v2f __attribute__((ext_vector_type(2)));

// Opaque-ify a float so the compiler cannot rematerialize it from memory.
__device__ __forceinline__ void pin(float& x) { asm volatile("" : "+v"(x)); }

// elementwise max on v2f (exact, order-free)
__device__ __forceinline__ v2f v2max(v2f a, v2f b) {
  v2f r;
  r.x = fmaxf(a.x, b.x);
  r.y = fmaxf(a.y, b.y);
  return r;
}

// ---------------------------------------------------------------------------
// 64-bit max/min reduction step via DPP (pure VALU, no ds_bpermute).
// Keys are positive finite doubles -> fmax/fmin == u64 max/min. old=own
// word + bound_ctrl=false => masked lanes yield own value (identity).
// After row_shr 1/2/4/8 + row_bcast15(0xa) + row_bcast31(0xc), lane 63
// holds the wave max/min. (HW-verified R5/R6/R8/R10)
// ---------------------------------------------------------------------------
template <int CTRL, int RMASK>
__device__ __forceinline__ double dppmax(double k) {
  const long long kb = __double_as_longlong(k);
  const int lo = (int)(kb & 0xffffffffll);
  const int hi = (int)(((unsigned long long)kb) >> 32);
  const int plo = __builtin_amdgcn_update_dpp(lo, lo, CTRL, RMASK, 0xf, false);
  const int phi = __builtin_amdgcn_update_dpp(hi, hi, CTRL, RMASK, 0xf, false);
  const double p =
      __longlong_as_double(((long long)phi << 32) | (unsigned int)plo);
  return fmax(k, p);
}
template <int CTRL, int RMASK>
__device__ __forceinline__ double dppmin(double k) {
  const long long kb = __double_as_longlong(k);
  const int lo = (int)(kb & 0xffffffffll);
  const int hi = (int)(((unsigned long long)kb) >> 32);
  const int plo = __builtin_amdgcn_update_dpp(lo, lo, CTRL, RMASK, 0xf, false);
  const int phi = __builtin_amdgcn_update_dpp(hi, hi, CTRL, RMASK, 0xf, false);
  const double p =
      __longlong_as_double(((long long)phi << 32) | (unsigned int)plo);
  return fmin(k, p);
}

// ---------------------------------------------------------------------------
// FPS (R8/R10-verified v8 algorithm) split into two launches so the idle
// 252 CUs can run first-half kNN under the second half:
//   fps_a: Morton sort + iterations 0..1023 (epoch-1 new_xyz flush at 1023),
//          then bit-spill state: d[] (raw), invw (raw), cached winner coords
//          + iwin flag (raw), per-wave keylow (raw), next centroid (raw).
//          tmax and per-thread bbox are exact recomputes in part b
//          (tmax == max(d) is an invariant of the v8 loop).
//   fps_b: reload, iterations 1024..2047 (epoch-2 flush at 2047).
// Selection algebra, key layout (tagged ds_max_u64), and all FP arithmetic
// identical to v8 -> FPS trajectory bit-exact (jnp.argmax first-match).
// (R11 fix: fp contract(off) pragma must open a compound statement; the
//  fps-b body lives in its own device function with the pragma at its top.)
// ---------------------------------------------------------------------------
__global__ __attribute__((amdgpu_flat_work_group_size(1024, 1024),
                          amdgpu_waves_per_eu(4, 4)))
void fps_a_kernel(const float* __restrict__ xyz, float* __restrict__ new_xyz,
                  float* __restrict__ sortbuf, float* __restrict__ dsp,
                  float4* __restrict__ ccsp, unsigned int* __restrict__ invsp,
                  unsigned long long* __restrict__ klsp,
                  float4* __restrict__ csp) {
#pragma clang fp contract(off)
  const int b = blockIdx.x;
  const float* X = xyz + (size_t)b * N_ * 3;
  float* SB = sortbuf + (size_t)b * 3 * N_;
  const int t = threadIdx.x;
  constexpr int PAIRS = N_ / 1024 / 2;  // 8 pairs = 16 points/thread
  const int base = t * (2 * PAIRS);

  __shared__ unsigned int s_hist[4096];
  __shared__ float s_bb[16][8];
  __shared__ unsigned int s_wsum[16];
  __shared__ unsigned short s_sidx[N_];
  __shared__ unsigned long long s_k1[2];
  __shared__ __align__(16) float4 s_cc[2][16];

  // ---- load my 16 original points ----
  float arr[48];
  {
    float4* a4 = (float4*)arr;
#pragma unroll
    for (int i = 0; i < 12; ++i) a4[i] = *(const float4*)(X + base * 3 + 4 * i);
  }
  // ---- block bbox ----
  float lx0 = arr[0], lx1 = arr[0], ly0 = arr[1], ly1 = arr[1];
  float lz0 = arr[2], lz1 = arr[2];
#pragma unroll
  for (int p = 1; p < 16; ++p) {
    lx0 = fminf(lx0, arr[3 * p + 0]); lx1 = fmaxf(lx1, arr[3 * p + 0]);
    ly0 = fminf(ly0, arr[3 * p + 1]); ly1 = fmaxf(ly1, arr[3 * p + 1]);
    lz0 = fminf(lz0, arr[3 * p + 2]); lz1 = fmaxf(lz1, arr[3 * p + 2]);
  }
#pragma unroll
  for (int off = 32; off > 0; off >>= 1) {
    lx0 = fminf(lx0, __shfl_xor(lx0, off)); lx1 = fmaxf(lx1, __shfl_xor(lx1, off));
    ly0 = fminf(ly0, __shfl_xor(ly0, off)); ly1 = fmaxf(ly1, __shfl_xor(ly1, off));
    lz0 = fminf(lz0, __shfl_xor(lz0, off)); lz1 = fmaxf(lz1, __shfl_xor(lz1, off));
  }
  if ((t & 63) == 0) {
    const int w = t >> 6;
    s_bb[w][0] = lx0; s_bb[w][1] = lx1; s_bb[w][2] = ly0;
    s_bb[w][3] = ly1; s_bb[w][4] = lz0; s_bb[w][5] = lz1;
  }
  for (int i = t; i < 4096; i += 1024) s_hist[i] = 0u;
  if (t == 0) { s_k1[0] = 0ull; s_k1[1] = 0ull; }
  __syncthreads();
  float gx0 = s_bb[0][0], gx1 = s_bb[0][1], gy0 = s_bb[0][2];
  float gy1 = s_bb[0][3], gz0 = s_bb[0][4], gz1 = s_bb[0][5];
#pragma unroll
  for (int w = 1; w < 16; ++w) {
    gx0 = fminf(gx0, s_bb[w][0]); gx1 = fmaxf(gx1, s_bb[w][1]);
    gy0 = fminf(gy0, s_bb[w][2]); gy1 = fmaxf(gy1, s_bb[w][3]);
    gz0 = fminf(gz0, s_bb[w][4]); gz1 = fmaxf(gz1, s_bb[w][5]);
  }
  const float ivx = (gx1 > gx0) ? 16.0f / (gx1 - gx0) : 0.0f;
  const float ivy = (gy1 > gy0) ? 16.0f / (gy1 - gy0) : 0.0f;
  const float ivz = (gz1 > gz0) ? 16.0f / (gz1 - gz0) : 0.0f;
  // ---- Morton cell per point + histogram ----
  int cell[16];
#pragma unroll
  for (int p = 0; p < 16; ++p) {
    int qx = min(15, (int)((arr[3 * p + 0] - gx0) * ivx));
    int qy = min(15, (int)((arr[3 * p + 1] - gy0) * ivy));
    int qz = min(15, (int)((arr[3 * p + 2] - gz0) * ivz));
    int mx = (qx & 1) | ((qx & 2) << 2) | ((qx & 4) << 4) | ((qx & 8) << 6);
    int my = (qy & 1) | ((qy & 2) << 2) | ((qy & 4) << 4) | ((qy & 8) << 6);
    int mz = (qz & 1) | ((qz & 2) << 2) | ((qz & 4) << 4) | ((qz & 8) << 6);
    cell[p] = mx | (my << 1) | (mz << 2);
    atomicAdd(&s_hist[cell[p]], 1u);
  }
  __syncthreads();
  // ---- exclusive scan of 4096 bins ----
  {
    unsigned int c0 = s_hist[4 * t + 0], c1 = s_hist[4 * t + 1];
    unsigned int c2 = s_hist[4 * t + 2], c3 = s_hist[4 * t + 3];
    (void)c3;
    unsigned int tsum = c0 + c1 + c2 + c3;
    unsigned int incl = tsum;
#pragma unroll
    for (int off = 1; off < 64; off <<= 1) {
      unsigned int nv = __shfl_up(incl, off);
      if ((t & 63) >= off) incl += nv;
    }
    if ((t & 63) == 63) s_wsum[t >> 6] = incl;
    __syncthreads();
    unsigned int wpre = 0;
    const int myw = t >> 6;
    for (int w = 0; w < myw; ++w) wpre += s_wsum[w];
    const unsigned int texc = wpre + incl - tsum;
    s_hist[4 * t + 0] = texc;
    s_hist[4 * t + 1] = texc + c0;
    s_hist[4 * t + 2] = texc + c0 + c1;
    s_hist[4 * t + 3] = texc + c0 + c1 + c2;
  }
  __syncthreads();
  // ---- scatter points + orig indices ----
#pragma unroll
  for (int p = 0; p < 16; ++p) {
    const unsigned int slot = atomicAdd(&s_hist[cell[p]], 1u);
    SB[slot]          = arr[3 * p + 0];
    SB[N_ + slot]     = arr[3 * p + 1];
    SB[2 * N_ + slot] = arr[3 * p + 2];
    s_sidx[slot] = (unsigned short)(base + p);
  }
  __threadfence();
  __syncthreads();
  __threadfence();

  // ---- reload sorted points ----
  v2f px[PAIRS], py[PAIRS], pz[PAIRS], d[PAIRS];
  {
    float4 xa[4], ya[4], za[4];
#pragma unroll
    for (int i = 0; i < 4; ++i) {
      xa[i] = *(const float4*)(SB + base + 4 * i);
      ya[i] = *(const float4*)(SB + N_ + base + 4 * i);
      za[i] = *(const float4*)(SB + 2 * N_ + base + 4 * i);
    }
    const float* xf = (const float*)xa;
    const float* yf = (const float*)ya;
    const float* zf = (const float*)za;
#pragma unroll
    for (int j = 0; j < PAIRS; ++j) {
      px[j] = (v2f){xf[2 * j], xf[2 * j + 1]};
      py[j] = (v2f){yf[2 * j], yf[2 * j + 1]};
      pz[j] = (v2f){zf[2 * j], zf[2 * j + 1]};
      d[j] = (v2f){1e10f, 1e10f};
    }
  }
  unsigned int invw[PAIRS];
  {
    const unsigned int* SI = (const unsigned int*)&s_sidx[base];
#pragma unroll
    for (int j = 0; j < PAIRS; ++j) invw[j] = ~SI[j];
  }
  float bx0 = 1e30f, bx1 = -1e30f, by0 = 1e30f, by1 = -1e30f;
  float bz0 = 1e30f, bz1 = -1e30f;
#pragma unroll
  for (int j = 0; j < PAIRS; ++j) {
    bx0 = fminf(bx0, fminf(px[j].x, px[j].y));
    bx1 = fmaxf(bx1, fmaxf(px[j].x, px[j].y));
    by0 = fminf(by0, fminf(py[j].x, py[j].y));
    by1 = fmaxf(by1, fmaxf(py[j].x, py[j].y));
    bz0 = fminf(bz0, fminf(pz[j].x, pz[j].y));
    bz1 = fmaxf(bz1, fmaxf(pz[j].x, pz[j].y));
  }
#pragma unroll
  for (int j = 0; j < PAIRS; ++j) {
    float a0 = px[j].x, a1 = px[j].y;
    float b0 = py[j].x, b1 = py[j].y;
    float c0 = pz[j].x, c1 = pz[j].y;
    pin(a0); pin(a1); pin(b0); pin(b1); pin(c0); pin(c1);
    px[j] = (v2f){a0, a1};
    py[j] = (v2f){b0, b1};
    pz[j] = (v2f){c0, c1};
  }
  float cx = X[0], cy = X[1], cz = X[2];
  float tmax = 1e10f;
  unsigned long long keylow = 0ull;
  bool iwin = false;
  float ccx = 0.f, ccy = 0.f, ccz = 0.f;
  float cap_x = 0.f, cap_y = 0.f, cap_z = 0.f;
  const unsigned int wid = (unsigned int)(t >> 6);
  for (int s = 0; s < 1024; ++s) {  // first half; no break needed
    if (((s - t) & 1023) == 0) { cap_x = cx; cap_y = cy; cap_z = cz; }
    if ((s & 1023) == 1023) {  // epoch-1 flush
      const int o = (b * S_ + (s & ~1023) + t) * 3;
      new_xyz[o + 0] = cap_x;
      new_xyz[o + 1] = cap_y;
      new_xyz[o + 2] = cap_z;
    }
    const int buf = s & 1;
    const float mx = fmaxf(fmaxf(bx0 - cx, cx - bx1), 0.0f);
    const float my = fmaxf(fmaxf(by0 - cy, cy - by1), 0.0f);
    const float mz = fmaxf(fmaxf(bz0 - cz, cz - bz1), 0.0f);
    const float L = (mx * mx + my * my) + mz * mz;
    if (__any(L < tmax)) {
      __builtin_amdgcn_s_setprio(1);
      const v2f c2x = {cx, cx}, c2y = {cy, cy}, c2z = {cz, cz};
#pragma unroll
      for (int j = 0; j < PAIRS; ++j) {
        v2f dx = px[j] - c2x;
        v2f dy = py[j] - c2y;
        v2f dz = pz[j] - c2z;
        v2f sq = (dx * dx + dy * dy) + dz * dz;
        v2f dm;
        dm.x = fminf(d[j].x, sq.x);
        dm.y = fminf(d[j].y, sq.y);
        d[j] = dm;
      }
      const v2f m01 = v2max(d[0], d[1]);
      const v2f m23 = v2max(d[2], d[3]);
      const v2f m45 = v2max(d[4], d[5]);
      const v2f m67 = v2max(d[6], d[7]);
      const v2f m03 = v2max(m01, m23);
      const v2f m47 = v2max(m45, m67);
      const v2f m07 = v2max(m03, m47);
      const float lmax = fmaxf(m07.x, m07.y);
      tmax = lmax;
      unsigned int binv = 0u;
#pragma unroll
      for (int j = 0; j < PAIRS; ++j) {
        const unsigned int lo = invw[j] & 0xFFFFu;
        const unsigned int hi = invw[j] >> 16;
        if (d[j].x == lmax) binv = max(binv, lo);
        if (d[j].y == lmax) binv = max(binv, hi);
      }
#pragma unroll
      for (int j = 0; j < PAIRS; ++j) {
        const unsigned int lo = invw[j] & 0xFFFFu;
        const unsigned int hi = invw[j] >> 16;
        if (lo == binv) { ccx = px[j].x; ccy = py[j].x; ccz = pz[j].x; }
        if (hi == binv) { ccx = px[j].y; ccy = py[j].y; ccz = pz[j].y; }
      }
      const unsigned long long k52 =
          ((unsigned long long)__float_as_uint(lmax) << 20) |
          (unsigned long long)((binv << 4) | wid);
      double dk = __longlong_as_double((long long)k52);
      dk = dppmax<0x111, 0xf>(dk);
      dk = dppmax<0x112, 0xf>(dk);
      dk = dppmax<0x114, 0xf>(dk);
      dk = dppmax<0x118, 0xf>(dk);
      dk = dppmax<0x142, 0xa>(dk);
      dk = dppmax<0x143, 0xc>(dk);
      const long long kb = __double_as_longlong(dk);
      const int rlo = __builtin_amdgcn_readlane((int)(kb & 0xffffffffll), 63);
      const int rhi =
          __builtin_amdgcn_readlane((int)(((unsigned long long)kb) >> 32), 63);
      const unsigned long long wk52 =
          ((unsigned long long)(unsigned int)rhi << 32) | (unsigned int)rlo;
      iwin = (k52 == wk52);
      keylow = wk52;
      __builtin_amdgcn_s_setprio(0);
    }
    if (iwin) {
      atomicMax(&s_k1[buf], ((unsigned long long)s << 52) | keylow);
      s_cc[buf][wid] = make_float4(ccx, ccy, ccz, 0.f);
    }
    __syncthreads();
    const unsigned long long bk = s_k1[buf];
    const int w_win = (int)(bk & 15ull);
    const float4 cc = s_cc[buf][w_win];
    cx = cc.x; cy = cc.y; cz = cc.z;
  }
  // ---- bit-exact state spill ----
  {
    float4* o = (float4*)(dsp + ((size_t)b * 1024 + t) * 16);
    o[0] = make_float4(d[0].x, d[0].y, d[1].x, d[1].y);
    o[1] = make_float4(d[2].x, d[2].y, d[3].x, d[3].y);
    o[2] = make_float4(d[4].x, d[4].y, d[5].x, d[5].y);
    o[3] = make_float4(d[6].x, d[6].y, d[7].x, d[7].y);
    ccsp[b * 1024 + t] = make_float4(ccx, ccy, ccz, iwin ? 1.f : 0.f);
    unsigned int* iv = invsp + ((size_t)b * 1024 + t) * 8;
#pragma unroll
    for (int j = 0; j < PAIRS; ++j) iv[j] = invw[j];
    if ((t & 63) == 0) klsp[b * 16 + wid] = keylow;
    if (t == 0) csp[b] = make_float4(cx, cy, cz, 0.f);
  }
}

// ---------------------------------------------------------------------------
// fps part b body (pragma at compound-statement start -> legal; inlined
// into the fused kernel with contract(off) semantics preserved).
// ---------------------------------------------------------------------------
__device__ void fps_b_body(const float* __restrict__ xyz,
                           float* __restrict__ new_xyz,
                           float* __restrict__ sortbuf,
                           float* __restrict__ dsp, float4* __restrict__ ccsp,
                           unsigned int* __restrict__ invsp,
                           unsigned long long* __restrict__ klsp,
                           float4* __restrict__ csp, char* smem) {
#pragma clang fp contract(off)
  const int b = blockIdx.x;
  const float* X = xyz + (size_t)b * N_ * 3;
  float* SB = sortbuf + (size_t)b * 3 * N_;
  const int t = threadIdx.x;
  constexpr int PAIRS = N_ / 1024 / 2;
  const int base = t * (2 * PAIRS);
  unsigned long long* s_k1 = (unsigned long long*)smem;
  float4* s_cc = (float4*)(smem + 32);  // [2][16] float4
  (void)X;

  // ---- reload sorted points (exact same values as fps_a) ----
  v2f px[PAIRS], py[PAIRS], pz[PAIRS], d[PAIRS];
  {
    float4 xa[4], ya[4], za[4];
#pragma unroll
    for (int i = 0; i < 4; ++i) {
      xa[i] = *(const float4*)(SB + base + 4 * i);
      ya[i] = *(const float4*)(SB + N_ + base + 4 * i);
      za[i] = *(const float4*)(SB + 2 * N_ + base + 4 * i);
    }
    const float* xf = (const float*)xa;
    const float* yf = (const float*)ya;
    const float* zf = (const float*)za;
#pragma unroll
    for (int j = 0; j < PAIRS; ++j) {
      px[j] = (v2f){xf[2 * j], xf[2 * j + 1]};
      py[j] = (v2f){yf[2 * j], yf[2 * j + 1]};
      pz[j] = (v2f){zf[2 * j], zf[2 * j + 1]};
    }
  }
  // ---- reload spilled state (raw bit copies) ----
  {
    const float4* i4 = (const float4*)(dsp + ((size_t)b * 1024 + t) * 16);
    float4 d0 = i4[0], d1 = i4[1], d2 = i4[2], d3 = i4[3];
    d[0] = (v2f){d0.x, d0.y}; d[1] = (v2f){d0.z, d0.w};
    d[2] = (v2f){d1.x, d1.y}; d[3] = (v2f){d1.z, d1.w};
    d[4] = (v2f){d2.x, d2.y}; d[5] = (v2f){d2.z, d2.w};
    d[6] = (v2f){d3.x, d3.y}; d[7] = (v2f){d3.z, d3.w};
  }
  unsigned int invw[PAIRS];
  {
    const unsigned int* iv = invsp + ((size_t)b * 1024 + t) * 8;
#pragma unroll
    for (int j = 0; j < PAIRS; ++j) invw[j] = iv[j];
  }
  const float4 ccv = ccsp[b * 1024 + t];
  float ccx = ccv.x, ccy = ccv.y, ccz = ccv.z;
  bool iwin = (ccv.w != 0.f);
  const unsigned int wid = (unsigned int)(t >> 6);
  unsigned long long keylow = klsp[b * 16 + wid];  // wave-uniform
  const float4 cv = csp[b];
  float cx = cv.x, cy = cv.y, cz = cv.z;
  // tmax == max(d) invariant -> exact recompute
  float tmax;
  {
    const v2f m01 = v2max(d[0], d[1]);
    const v2f m23 = v2max(d[2], d[3]);
    const v2f m45 = v2max(d[4], d[5]);
    const v2f m67 = v2max(d[6], d[7]);
    const v2f m03 = v2max(m01, m23);
    const v2f m47 = v2max(m45, m67);
    const v2f m07 = v2max(m03, m47);
    tmax = fmaxf(m07.x, m07.y);
  }
  // per-thread bbox: exact recompute from identical points
  float bx0 = 1e30f, bx1 = -1e30f, by0 = 1e30f, by1 = -1e30f;
  float bz0 = 1e30f, bz1 = -1e30f;
#pragma unroll
  for (int j = 0; j < PAIRS; ++j) {
    bx0 = fminf(bx0, fminf(px[j].x, px[j].y));
    bx1 = fmaxf(bx1, fmaxf(px[j].x, px[j].y));
    by0 = fminf(by0, fminf(py[j].x, py[j].y));
    by1 = fmaxf(by1, fmaxf(py[j].x, py[j].y));
    bz0 = fminf(bz0, fminf(pz[j].x, pz[j].y));
    bz1 = fmaxf(bz1, fmaxf(pz[j].x, pz[j].y));
  }
#pragma unroll
  for (int j = 0; j < PAIRS; ++j) {
    float a0 = px[j].x, a1 = px[j].y;
    float b0 = py[j].x, b1 = py[j].y;
    float c0 = pz[j].x, c1 = pz[j].y;
    pin(a0); pin(a1); pin(b0); pin(b1); pin(c0); pin(c1);
    px[j] = (v2f){a0, a1};
    py[j] = (v2f){b0, b1};
    pz[j] = (v2f){c0, c1};
  }
  if (t == 0) { s_k1[0] = 0ull; s_k1[1] = 0ull; }  // stale tags < 1024 lose
  __syncthreads();
  float cap_x = 0.f, cap_y = 0.f, cap_z = 0.f;
  for (int s = 1024; s < S_; ++s) {
    if (((s - t) & 1023) == 0) { cap_x = cx; cap_y = cy; cap_z = cz; }
    if ((s & 1023) == 1023) {  // epoch-2 flush
      const int o = (b * S_ + (s & ~1023) + t) * 3;
      new_xyz[o + 0] = cap_x;
      new_xyz[o + 1] = cap_y;
      new_xyz[o + 2] = cap_z;
    }
    if (s == S_ - 1) break;
    const int buf = s & 1;
    const float mx = fmaxf(fmaxf(bx0 - cx, cx - bx1), 0.0f);
    const float my = fmaxf(fmaxf(by0 - cy, cy - by1), 0.0f);
    const float mz = fmaxf(fmaxf(bz0 - cz, cz - bz1), 0.0f);
    const float L = (mx * mx + my * my) + mz * mz;
    if (__any(L < tmax)) {
      __builtin_amdgcn_s_setprio(1);
      const v2f c2x = {cx, cx}, c2y = {cy, cy}, c2z = {cz, cz};
#pragma unroll
      for (int j = 0; j < PAIRS; ++j) {
        v2f dx = px[j] - c2x;
        v2f dy = py[j] - c2y;
        v2f dz = pz[j] - c2z;
        v2f sq = (dx * dx + dy * dy) + dz * dz;
        v2f dm;
        dm.x = fminf(d[j].x, sq.x);
        dm.y = fminf(d[j].y, sq.y);
        d[j] = dm;
      }
      const v2f m01 = v2max(d[0], d[1]);
      const v2f m23 = v2max(d[2], d[3]);
      const v2f m45 = v2max(d[4], d[5]);
      const v2f m67 = v2max(d[6], d[7]);
      const v2f m03 = v2max(m01, m23);
      const v2f m47 = v2max(m45, m67);
      const v2f m07 = v2max(m03, m47);
      const float lmax = fmaxf(m07.x, m07.y);
      tmax = lmax;
      unsigned int binv = 0u;
#pragma unroll
      for (int j = 0; j < PAIRS; ++j) {
        const unsigned int lo = invw[j] & 0xFFFFu;
        const unsigned int hi = invw[j] >> 16;
        if (d[j].x == lmax) binv = max(binv, lo);
        if (d[j].y == lmax) binv = max(binv, hi);
      }
#pragma unroll
      for (int j = 0; j < PAIRS; ++j) {
        const unsigned int lo = invw[j] & 0xFFFFu;
        const unsigned int hi = invw[j] >> 16;
        if (lo == binv) { ccx = px[j].x; ccy = py[j].x; ccz = pz[j].x; }
        if (hi == binv) { ccx = px[j].y; ccy = py[j].y; ccz = pz[j].y; }
      }
      const unsigned long long k52 =
          ((unsigned long long)__float_as_uint(lmax) << 20) |
          (unsigned long long)((binv << 4) | wid);
      double dk = __longlong_as_double((long long)k52);
      dk = dppmax<0x111, 0xf>(dk);
      dk = dppmax<0x112, 0xf>(dk);
      dk = dppmax<0x114, 0xf>(dk);
      dk = dppmax<0x118, 0xf>(dk);
      dk = dppmax<0x142, 0xa>(dk);
      dk = dppmax<0x143, 0xc>(dk);
      const long long kb = __double_as_longlong(dk);
      const int rlo = __builtin_amdgcn_readlane((int)(kb & 0xffffffffll), 63);
      const int rhi =
          __builtin_amdgcn_readlane((int)(((unsigned long long)kb) >> 32), 63);
      const unsigned long long wk52 =
          ((unsigned long long)(unsigned int)rhi << 32) | (unsigned int)rlo;
      iwin = (k52 == wk52);
      keylow = wk52;
      __builtin_amdgcn_s_setprio(0);
    }
    if (iwin) {
      atomicMax(&s_k1[buf], ((unsigned long long)s << 52) | keylow);
      s_cc[buf * 16 + wid] = make_float4(ccx, ccy, ccz, 0.f);
    }
    __syncthreads();
    const unsigned long long bk = s_k1[buf];
    const int w_win = (int)(bk & 15ull);
    const float4 cc = s_cc[buf * 16 + w_win];
    cx = cc.x; cy = cc.y; cz = cc.z;
  }
}

// ---------------------------------------------------------------------------
// kNN core @1024 threads (R10-verified tag/atomic/DPP scheme, 16 pts/thread)
// ---------------------------------------------------------------------------
__device__ __forceinline__ void knn_core(float* sd, unsigned long long* s_kd,
                                         const float* __restrict__ xyz,
                                         const float* __restrict__ new_xyz,
                                         int* __restrict__ knn_idx, int q,
                                         int b) {
  const int t = threadIdx.x;
  if (t == 0) { s_kd[0] = ~0ull; s_kd[1] = ~0ull; }
  const float qx = new_xyz[q * 3 + 0];
  const float qy = new_xyz[q * 3 + 1];
  const float qz = new_xyz[q * 3 + 2];
  const float* X = xyz + (size_t)b * N_ * 3;
  float lmin = 1e30f;
  int lidx = -1;
  for (int j = 0; j < N_ / 1024; ++j) {
    int i = t + j * 1024;
    float dx = X[i * 3 + 0] - qx;
    float dy = X[i * 3 + 1] - qy;
    float dz = X[i * 3 + 2] - qz;
    float dsq = fmaf(dx, dx, fmaf(dy, dy, dz * dz));
    sd[i] = dsq;
    if (dsq < lmin) { lmin = dsq; lidx = i; }
  }
  __syncthreads();
  for (int r = 0; r < K_; ++r) {
    const unsigned long long k =
        ((unsigned long long)(7 - (r >> 1)) << 60) |
        ((unsigned long long)__float_as_uint(lmin) << 28) |
        (unsigned int)(lidx & 0x0FFFFFFF);
    double dk = __longlong_as_double((long long)k);
    dk = dppmin<0x111, 0xf>(dk);
    dk = dppmin<0x112, 0xf>(dk);
    dk = dppmin<0x114, 0xf>(dk);
    dk = dppmin<0x118, 0xf>(dk);
    dk = dppmin<0x142, 0xa>(dk);
    dk = dppmin<0x143, 0xc>(dk);
    const long long kb = __double_as_longlong(dk);
    const int rlo = __builtin_amdgcn_readlane((int)(kb & 0xffffffffll), 63);
    const int rhi =
        __builtin_amdgcn_readlane((int)(((unsigned long long)kb) >> 32), 63);
    const unsigned long long wk =
        ((unsigned long long)(unsigned int)rhi << 32) | (unsigned int)rlo;
    if ((t & 63) == 0) atomicMin(&s_kd[r & 1], wk);
    __syncthreads();
    const unsigned long long bk = s_kd[r & 1];
    const int wi = (int)(bk & 0x0FFFFFFFull);
    if (t == 0) knn_idx[q * K_ + r] = wi;
    if (wi == lidx) {  // unique owner (disjoint stripes)
      sd[wi] = 1e30f;
      lmin = 1e30f; lidx = -1;
      for (int j = 0; j < N_ / 1024; ++j) {
        int i = t + j * 1024;
        float dv = sd[i];
        if (dv < lmin) { lmin = dv; lidx = i; }
      }
    }
  }
}

// ---------------------------------------------------------------------------
// Fused launch 2: blocks 0..B_-1 resume fps (iters 1024..2047); blocks
// B_.. run kNN for first-half queries (s<1024, new_xyz written by fps_a).
// Roles are independent -> any scheduling order correct. waves_per_eu(4,4)
// forces 1 block/CU so the 4 fps CUs run solo (exact v8 conditions).
// ---------------------------------------------------------------------------
__global__ __attribute__((amdgpu_flat_work_group_size(1024, 1024),
                          amdgpu_waves_per_eu(4, 4)))
void fused_b_kernel(const float* __restrict__ xyz, float* __restrict__ new_xyz,
                    float* __restrict__ sortbuf, float* __restrict__ dsp,
                    float4* __restrict__ ccsp, unsigned int* __restrict__ invsp,
                    unsigned long long* __restrict__ klsp,
                    float4* __restrict__ csp, int* __restrict__ knn_idx) {
  __shared__ __align__(16) char smem[N_ * 4 + 16];  // 64KB sd | 16B slots
  if (blockIdx.x >= B_) {
    const int idx = blockIdx.x - B_;
    const int b = idx >> 10;
    const int s = idx & 1023;  // first half
    knn_core((float*)smem, (unsigned long long*)(smem + N_ * 4), xyz, new_xyz,
             knn_idx, b * S_ + s, b);
    return;
  }
  fps_b_body(xyz, new_xyz, sortbuf, dsp, ccsp, invsp, klsp, csp, smem);
}

// ---------------------------------------------------------------------------
// kNN second half: standalone, 2 blocks/CU.
// ---------------------------------------------------------------------------
__global__ __attribute__((amdgpu_flat_work_group_size(1024, 1024)))
void knn2_kernel(const float* __restrict__ xyz,
                 const float* __restrict__ new_xyz, int* __restrict__ knn_idx) {
  __shared__ float sd[N_];
  __shared__ unsigned long long s_kd[2];
  const int idx = blockIdx.x;
  const int b = idx >> 10;
  const int s = 1024 + (idx & 1023);
  knn_core(sd, s_kd, xyz, new_xyz, knn_idx, b * S_ + s, b);
}

// ---------------------------------------------------------------------------
// Transpose weights + zero stats (unchanged).
// ---------------------------------------------------------------------------
__global__ __launch_bounds__(256) void prep_kernel(const float* __restrict__ W1,
                                                   const float* __restrict__ W2,
                                                   float* __restrict__ W1t,
                                                   float* __restrict__ W2t,
                                                   float* __restrict__ stats) {
  int e = blockIdx.x * 256 + threadIdx.x;
  stats[e] = 0.0f;
  if (e < C1_ * C0_) {
    int co = e / C0_, c = e % C0_;
    W1t[c * C1_ + co] = W1[e];
  } else {
    int e2 = e - C1_ * C0_;
    int co = e2 / C1_, c = e2 % C1_;
    W2t[c * C2_ + co] = W2[e2];
  }
}

// ---------------------------------------------------------------------------
// conv1 stats (unchanged).
// ---------------------------------------------------------------------------
__global__ __launch_bounds__(256) void conv1_stats_kernel(
    const float* __restrict__ xyz, const float* __restrict__ feat,
    const float* __restrict__ new_xyz, const int* __restrict__ knn,
    const float* __restrict__ W1t, const float* __restrict__ b1,
    float* __restrict__ stats1) {
  __shared__ __align__(16) float sinT[C0_][K_];
  __shared__ int sidx[K_];
  __shared__ float sred[256];
  const int t = threadIdx.x;
  float psum = 0.f, psumsq = 0.f;
  const int QPB = (B_ * S_) / 1024;
  for (int qq = 0; qq < QPB; ++qq) {
    const int q = blockIdx.x * QPB + qq;
    const int b = q / S_;
    if (t < K_) sidx[t] = knn[q * K_ + t];
    __syncthreads();
    const float nx = new_xyz[q * 3 + 0];
    const float ny = new_xyz[q * 3 + 1];
    const float nz = new_xyz[q * 3 + 2];
    for (int e = t; e < K_ * C0_; e += 256) {
      int c = e >> 4, kk = e & 15;
      int i = sidx[kk];
      float v;
      if (c < 3)
        v = xyz[((size_t)b * N_ + i) * 3 + c] - (c == 0 ? nx : (c == 1 ? ny : nz));
      else
        v = feat[((size_t)b * N_ + i) * D_ + (c - 3)];
      sinT[c][kk] = v;
    }
    __syncthreads();
    const int co = t & 127, kh = t >> 7;
    float acc[8];
    float bias = b1[co];
#pragma unroll
    for (int k = 0; k < 8; ++k) acc[k] = bias;
    for (int c = 0; c < C0_; ++c) {
      float w = W1t[c * C1_ + co];
      float4 xa = *(const float4*)&sinT[c][kh * 8];
      float4 xb = *(const float4*)&sinT[c][kh * 8 + 4];
      acc[0] = fmaf(w, xa.x, acc[0]);
      acc[1] = fmaf(w, xa.y, acc[1]);
      acc[2] = fmaf(w, xa.z, acc[2]);
      acc[3] = fmaf(w, xa.w, acc[3]);
      acc[4] = fmaf(w, xb.x, acc[4]);
      acc[5] = fmaf(w, xb.y, acc[5]);
      acc[6] = fmaf(w, xb.z, acc[6]);
      acc[7] = fmaf(w, xb.w, acc[7]);
    }
#pragma unroll
    for (int k = 0; k < 8; ++k) {
      psum += acc[k];
      psumsq = fmaf(acc[k], acc[k], psumsq);
    }
    __syncthreads();
  }
  sred[t] = psum;
  __syncthreads();
  float totsum = (t < 128) ? (sred[t] + sred[t + 128]) : 0.f;
  __syncthreads();
  sred[t] = psumsq;
  __syncthreads();
  if (t < 128) {
    float totsq = sred[t] + sred[t + 128];
    float* st = stats1 + (size_t)(blockIdx.x & (NSLOT - 1)) * (2 * C1_);
    atomicAdd(&st[t], totsum);
    atomicAdd(&st[C1_ + t], totsq);
  }
}

__global__ void finalize1_kernel(const float* __restrict__ stats1,
                                 const float* __restrict__ gamma1,
                                 const float* __restrict__ beta1,
                                 float* __restrict__ ss1) {
  int t = threadIdx.x;
  float s = 0.f, sq = 0.f;
  for (int w = 0; w < NSLOT; ++w) {
    s += stats1[w * 2 * C1_ + t];
    sq += stats1[w * 2 * C1_ + C1_ + t];
  }
  const float M = (float)(B_ * S_ * K_);
  float m = s / M;
  float v = fmaxf(sq / M - m * m, 0.f);
  float sc = gamma1[t] * rsqrtf(v + 1e-5f);
  ss1[t] = sc;
  ss1[C1_ + t] = fmaf(-m, sc, beta1[t]);
}

// ---------------------------------------------------------------------------
// conv2 (unchanged).
// ---------------------------------------------------------------------------
__global__ __launch_bounds__(256) void conv2_kernel(
    const float* __restrict__ xyz, const float* __restrict__ feat,
    const float* __restrict__ new_xyz, const int* __restrict__ knn,
    const float* __restrict__ W1t, const float* __restrict__ b1,
    const float* __restrict__ ss1, const float* __restrict__ W2t,
    const float* __restrict__ b2, float* __restrict__ maxv,
    float* __restrict__ minv, float* __restrict__ stats2) {
  __shared__ __align__(16) float sinT[C0_][K_];
  __shared__ __align__(16) float sh1T[C1_][20];
  __shared__ int sidx[K_];
  const int t = threadIdx.x;
  float psum = 0.f, psumsq = 0.f;
  const int QPB = (B_ * S_) / 1024;
  for (int qq = 0; qq < QPB; ++qq) {
    const int q = blockIdx.x * QPB + qq;
    const int b = q / S_;
    if (t < K_) sidx[t] = knn[q * K_ + t];
    __syncthreads();
    const float nx = new_xyz[q * 3 + 0];
    const float ny = new_xyz[q * 3 + 1];
    const float nz = new_xyz[q * 3 + 2];
    for (int e = t; e < K_ * C0_; e += 256) {
      int c = e >> 4, kk = e & 15;
      int i = sidx[kk];
      float v;
      if (c < 3)
        v = xyz[((size_t)b * N_ + i) * 3 + c] - (c == 0 ? nx : (c == 1 ? ny : nz));
      else
        v = feat[((size_t)b * N_ + i) * D_ + (c - 3)];
      sinT[c][kk] = v;
    }
    __syncthreads();
    {
      const int co = t & 127, kh = t >> 7;
      float acc[8];
      float bias = b1[co];
#pragma unroll
      for (int k = 0; k < 8; ++k) acc[k] = bias;
      for (int c = 0; c < C0_; ++c) {
        float w = W1t[c * C1_ + co];
        float4 xa = *(const float4*)&sinT[c][kh * 8];
        float4 xb = *(const float4*)&sinT[c][kh * 8 + 4];
        acc[0] = fmaf(w, xa.x, acc[0]);
        acc[1] = fmaf(w, xa.y, acc[1]);
        acc[2] = fmaf(w, xa.z, acc[2]);
        acc[3] = fmaf(w, xa.w, acc[3]);
        acc[4] = fmaf(w, xb.x, acc[4]);
        acc[5] = fmaf(w, xb.y, acc[5]);
        acc[6] = fmaf(w, xb.z, acc[6]);
        acc[7] = fmaf(w, xb.w, acc[7]);
      }
      float sc = ss1[co], sh = ss1[C1_ + co];
#pragma unroll
      for (int k = 0; k < 8; ++k) {
        float h = fmaxf(fmaf(acc[k], sc, sh), 0.f);
        sh1T[co][kh * 8 + k] = h;
      }
    }
    __syncthreads();
    {
      float acc2[16];
      float bias2 = b2[t];
#pragma unroll
      for (int k = 0; k < 16; ++k) acc2[k] = bias2;
      for (int c = 0; c < C1_; ++c) {
        float w = W2t[c * C2_ + t];
        float4 h0 = *(const float4*)&sh1T[c][0];
        float4 h1 = *(const float4*)&sh1T[c][4];
        float4 h2 = *(const float4*)&sh1T[c][8];
        float4 h3 = *(const float4*)&sh1T[c][12];
        acc2[0] = fmaf(w, h0.x, acc2[0]);
        acc2[1] = fmaf(w, h0.y, acc2[1]);
        acc2[2] = fmaf(w, h0.z, acc2[2]);
        acc2[3] = fmaf(w, h0.w, acc2[3]);
        acc2[4] = fmaf(w, h1.x, acc2[4]);
        acc2[5] = fmaf(w, h1.y, acc2[5]);
        acc2[6] = fmaf(w, h1.z, acc2[6]);
        acc2[7] = fmaf(w, h1.w, acc2[7]);
        acc2[8] = fmaf(w, h2.x, acc2[8]);
        acc2[9] = fmaf(w, h2.y, acc2[9]);
        acc2[10] = fmaf(w, h2.z, acc2[10]);
        acc2[11] = fmaf(w, h2.w, acc2[11]);
        acc2[12] = fmaf(w, h3.x, acc2[12]);
        acc2[13] = fmaf(w, h3.y, acc2[13]);
        acc2[14] = fmaf(w, h3.z, acc2[14]);
        acc2[15] = fmaf(w, h3.w, acc2[15]);
      }
      float mx = acc2[0], mn = acc2[0];
#pragma unroll
      for (int k = 0; k < 16; ++k) {
        psum += acc2[k];
        psumsq = fmaf(acc2[k], acc2[k], psumsq);
        mx = fmaxf(mx, acc2[k]);
        mn = fminf(mn, acc2[k]);
      }
      maxv[(size_t)q * C2_ + t] = mx;
      minv[(size_t)q * C2_ + t] = mn;
    }
    __syncthreads();
  }
  float* st = stats2 + (size_t)(blockIdx.x & (NSLOT - 1)) * (2 * C2_);
  atomicAdd(&st[t], psum);
  atomicAdd(&st[C2_ + t], psumsq);
}

__global__ void finalize2_kernel(const float* __restrict__ stats2,
                                 const float* __restrict__ gamma2,
                                 const float* __restrict__ beta2,
                                 float* __restrict__ ss2) {
  int t = threadIdx.x;
  float s = 0.f, sq = 0.f;
  for (int w = 0; w < NSLOT; ++w) {
    s += stats2[w * 2 * C2_ + t];
    sq += stats2[w * 2 * C2_ + C2_ + t];
  }
  const float M = (float)(B_ * S_ * K_);
  float m = s / M;
  float v = fmaxf(sq / M - m * m, 0.f);
  float sc = gamma2[t] * rsqrtf(v + 1e-5f);
  ss2[t] = sc;
  ss2[C2_ + t] = fmaf(-m, sc, beta2[t]);
}

__global__ __launch_bounds__(256) void out_kernel(const float* __restrict__ maxv,
                                                  const float* __restrict__ minv,
                                                  const float* __restrict__ ss2,
                                                  float* __restrict__ out2) {
  int e = blockIdx.x * 256 + threadIdx.x;
  int co = e & (C2_ - 1);
  float sc = ss2[co], sh = ss2[C2_ + co];
  float v = (sc >= 0.f) ? maxv[e] : minv[e];
  out2[e] = fmaxf(fmaf(v, sc, sh), 0.f);
}

extern "C" void kernel_launch(void* const* d_in, const int* in_sizes, int n_in,
                              void* d_out, int out_size, void* d_ws, size_t ws_size,
                              hipStream_t stream) {
  (void)in_sizes; (void)n_in; (void)out_size; (void)ws_size;
  const float* xyz = (const float*)d_in[0];
  const float* feat = (const float*)d_in[1];
  const float* W1 = (const float*)d_in[2];
  const float* b1 = (const float*)d_in[3];
  const float* gamma1 = (const float*)d_in[4];
  const float* beta1 = (const float*)d_in[5];
  const float* W2 = (const float*)d_in[6];
  const float* b2 = (const float*)d_in[7];
  const float* gamma2 = (const float*)d_in[8];
  const float* beta2 = (const float*)d_in[9];

  float* out = (float*)d_out;
  float* new_xyz = out;                 // [B,S,3]
  float* out2 = out + B_ * S_ * 3;      // [B,S,C2]

  float* ws = (float*)d_ws;
  float* stats1 = ws;                              // 64*256
  float* stats2 = stats1 + NSLOT * 2 * C1_;        // 64*512
  float* ss1 = stats2 + NSLOT * 2 * C2_;           // 256
  float* ss2 = ss1 + 2 * C1_;                      // 512
  float* W1t = ss2 + 2 * C2_;                      // 16384
  float* W2t = W1t + C1_ * C0_;                    // 32768
  int* knn = (int*)(W2t + (size_t)C2_ * C1_);      // B*S*K ints
  float* maxv = (float*)(knn + B_ * S_ * K_);      // B*S*C2
  float* minv = maxv + (size_t)B_ * S_ * C2_;      // B*S*C2
  // fps staging aliases dead conv2 outputs (conv2 runs after all fps/knn):
  //   sortbuf -> maxv region (3*N*B floats)
  //   spill   -> minv region (d 65536 fl | cc 16384 fl | invw 32768 u32 |
  //              keylow B*16 u64 | centroid B float4)
  float* sortbuf = maxv;
  float* dsp = minv;
  float4* ccsp = (float4*)(minv + 65536);
  unsigned int* invsp = (unsigned int*)(minv + 65536 + 16384);
  unsigned long long* klsp =
      (unsigned long long*)(minv + 65536 + 16384 + 32768);
  float4* csp = (float4*)(minv + 65536 + 16384 + 32768 + 2 * B_ * 16);

  prep_kernel<<<192, 256, 0, stream>>>(W1, W2, W1t, W2t, stats1);
  fps_a_kernel<<<B_, 1024, 0, stream>>>(xyz, new_xyz, sortbuf, dsp, ccsp,
                                        invsp, klsp, csp);
  fused_b_kernel<<<B_ + B_ * 1024, 1024, 0, stream>>>(
      xyz, new_xyz, sortbuf, dsp, ccsp, invsp, klsp, csp, knn);
  knn2_kernel<<<B_ * 1024, 1024, 0, stream>>>(xyz, new_xyz, knn);
  conv1_stats_kernel<<<1024, 256, 0, stream>>>(xyz, feat, new_xyz, knn, W1t, b1, stats1);
  finalize1_kernel<<<1, 128, 0, stream>>>(stats1, gamma1, beta1, ss1);
  conv2_kernel<<<1024, 256, 0, stream>>>(xyz, feat, new_xyz, knn, W1t, b1, ss1,
                                         W2t, b2, maxv, minv, stats2);
  finalize2_kernel<<<1, 256, 0, stream>>>(stats2, gamma2, beta2, ss2);
  out_kernel<<<(B_ * S_ * C2_) / 256, 256, 0, stream>>>(maxv, minv, ss2, out2);
}

// Round 13
// 3127.156 us; speedup vs baseline: 1.3991x; 1.0125x over previous
//
#include <hip/hip_runtime.h>

#define B_ 4
#define N_ 16384
#define D_ 125
#define S_ 2048
#define K_ 16
#define C0_ 128
#define C1_ 128
#define C2_ 256
#define NSLOT 64

typedef float v2f __attribute__((ext_vector_type(2)));

// Opaque-ify a float so the compiler cannot rematerialize it from memory.
__device__ __forceinline__ void pin(float& x) { asm volatile("" : "+v"(x)); }

// elementwise max on v2f (exact, order-free)
__device__ __forceinline__ v2f v2max(v2f a, v2f b) {
  v2f r;
  r.x = fmaxf(a.x, b.x);
  r.y = fmaxf(a.y, b.y);
  return r;
}

// ---------------------------------------------------------------------------
// 64-bit max/min reduction step via DPP (pure VALU, no ds_bpermute).
// Keys are positive finite doubles -> fmax/fmin == u64 max/min. old=own
// word + bound_ctrl=false => masked lanes yield own value (identity).
// After row_shr 1/2/4/8 + row_bcast15(0xa) + row_bcast31(0xc), lane 63
// holds the wave max/min. (HW-verified R5/R6/R8/R10/R12)
// ---------------------------------------------------------------------------
template <int CTRL, int RMASK>
__device__ __forceinline__ double dppmax(double k) {
  const long long kb = __double_as_longlong(k);
  const int lo = (int)(kb & 0xffffffffll);
  const int hi = (int)(((unsigned long long)kb) >> 32);
  const int plo = __builtin_amdgcn_update_dpp(lo, lo, CTRL, RMASK, 0xf, false);
  const int phi = __builtin_amdgcn_update_dpp(hi, hi, CTRL, RMASK, 0xf, false);
  const double p =
      __longlong_as_double(((long long)phi << 32) | (unsigned int)plo);
  return fmax(k, p);
}
template <int CTRL, int RMASK>
__device__ __forceinline__ double dppmin(double k) {
  const long long kb = __double_as_longlong(k);
  const int lo = (int)(kb & 0xffffffffll);
  const int hi = (int)(((unsigned long long)kb) >> 32);
  const int plo = __builtin_amdgcn_update_dpp(lo, lo, CTRL, RMASK, 0xf, false);
  const int phi = __builtin_amdgcn_update_dpp(hi, hi, CTRL, RMASK, 0xf, false);
  const double p =
      __longlong_as_double(((long long)phi << 32) | (unsigned int)plo);
  return fmin(k, p);
}

// ---------------------------------------------------------------------------
// FPS (R8/R10-verified v8 algorithm) split into two launches so the idle
// 252 CUs can run first-half kNN(+fused conv1) under the second half.
// fps_a: Morton sort + iterations 0..1023 + bit-exact state spill.
// fps_b (in fused_b): reload, iterations 1024..2047.
// Trajectory bit-exact (jnp.argmax first-match). fps closed per R7/R9.
// ---------------------------------------------------------------------------
__global__ __attribute__((amdgpu_flat_work_group_size(1024, 1024),
                          amdgpu_waves_per_eu(4, 4)))
void fps_a_kernel(const float* __restrict__ xyz, float* __restrict__ new_xyz,
                  float* __restrict__ sortbuf, float* __restrict__ dsp,
                  float4* __restrict__ ccsp, unsigned int* __restrict__ invsp,
                  unsigned long long* __restrict__ klsp,
                  float4* __restrict__ csp) {
#pragma clang fp contract(off)
  const int b = blockIdx.x;
  const float* X = xyz + (size_t)b * N_ * 3;
  float* SB = sortbuf + (size_t)b * 3 * N_;
  const int t = threadIdx.x;
  constexpr int PAIRS = N_ / 1024 / 2;  // 8 pairs = 16 points/thread
  const int base = t * (2 * PAIRS);

  __shared__ unsigned int s_hist[4096];
  __shared__ float s_bb[16][8];
  __shared__ unsigned int s_wsum[16];
  __shared__ unsigned short s_sidx[N_];
  __shared__ unsigned long long s_k1[2];
  __shared__ __align__(16) float4 s_cc[2][16];

  // ---- load my 16 original points ----
  float arr[48];
  {
    float4* a4 = (float4*)arr;
#pragma unroll
    for (int i = 0; i < 12; ++i) a4[i] = *(const float4*)(X + base * 3 + 4 * i);
  }
  // ---- block bbox ----
  float lx0 = arr[0], lx1 = arr[0], ly0 = arr[1], ly1 = arr[1];
  float lz0 = arr[2], lz1 = arr[2];
#pragma unroll
  for (int p = 1; p < 16; ++p) {
    lx0 = fminf(lx0, arr[3 * p + 0]); lx1 = fmaxf(lx1, arr[3 * p + 0]);
    ly0 = fminf(ly0, arr[3 * p + 1]); ly1 = fmaxf(ly1, arr[3 * p + 1]);
    lz0 = fminf(lz0, arr[3 * p + 2]); lz1 = fmaxf(lz1, arr[3 * p + 2]);
  }
#pragma unroll
  for (int off = 32; off > 0; off >>= 1) {
    lx0 = fminf(lx0, __shfl_xor(lx0, off)); lx1 = fmaxf(lx1, __shfl_xor(lx1, off));
    ly0 = fminf(ly0, __shfl_xor(ly0, off)); ly1 = fmaxf(ly1, __shfl_xor(ly1, off));
    lz0 = fminf(lz0, __shfl_xor(lz0, off)); lz1 = fmaxf(lz1, __shfl_xor(lz1, off));
  }
  if ((t & 63) == 0) {
    const int w = t >> 6;
    s_bb[w][0] = lx0; s_bb[w][1] = lx1; s_bb[w][2] = ly0;
    s_bb[w][3] = ly1; s_bb[w][4] = lz0; s_bb[w][5] = lz1;
  }
  for (int i = t; i < 4096; i += 1024) s_hist[i] = 0u;
  if (t == 0) { s_k1[0] = 0ull; s_k1[1] = 0ull; }
  __syncthreads();
  float gx0 = s_bb[0][0], gx1 = s_bb[0][1], gy0 = s_bb[0][2];
  float gy1 = s_bb[0][3], gz0 = s_bb[0][4], gz1 = s_bb[0][5];
#pragma unroll
  for (int w = 1; w < 16; ++w) {
    gx0 = fminf(gx0, s_bb[w][0]); gx1 = fmaxf(gx1, s_bb[w][1]);
    gy0 = fminf(gy0, s_bb[w][2]); gy1 = fmaxf(gy1, s_bb[w][3]);
    gz0 = fminf(gz0, s_bb[w][4]); gz1 = fmaxf(gz1, s_bb[w][5]);
  }
  const float ivx = (gx1 > gx0) ? 16.0f / (gx1 - gx0) : 0.0f;
  const float ivy = (gy1 > gy0) ? 16.0f / (gy1 - gy0) : 0.0f;
  const float ivz = (gz1 > gz0) ? 16.0f / (gz1 - gz0) : 0.0f;
  // ---- Morton cell per point + histogram ----
  int cell[16];
#pragma unroll
  for (int p = 0; p < 16; ++p) {
    int qx = min(15, (int)((arr[3 * p + 0] - gx0) * ivx));
    int qy = min(15, (int)((arr[3 * p + 1] - gy0) * ivy));
    int qz = min(15, (int)((arr[3 * p + 2] - gz0) * ivz));
    int mx = (qx & 1) | ((qx & 2) << 2) | ((qx & 4) << 4) | ((qx & 8) << 6);
    int my = (qy & 1) | ((qy & 2) << 2) | ((qy & 4) << 4) | ((qy & 8) << 6);
    int mz = (qz & 1) | ((qz & 2) << 2) | ((qz & 4) << 4) | ((qz & 8) << 6);
    cell[p] = mx | (my << 1) | (mz << 2);
    atomicAdd(&s_hist[cell[p]], 1u);
  }
  __syncthreads();
  // ---- exclusive scan of 4096 bins ----
  {
    unsigned int c0 = s_hist[4 * t + 0], c1 = s_hist[4 * t + 1];
    unsigned int c2 = s_hist[4 * t + 2], c3 = s_hist[4 * t + 3];
    (void)c3;
    unsigned int tsum = c0 + c1 + c2 + c3;
    unsigned int incl = tsum;
#pragma unroll
    for (int off = 1; off < 64; off <<= 1) {
      unsigned int nv = __shfl_up(incl, off);
      if ((t & 63) >= off) incl += nv;
    }
    if ((t & 63) == 63) s_wsum[t >> 6] = incl;
    __syncthreads();
    unsigned int wpre = 0;
    const int myw = t >> 6;
    for (int w = 0; w < myw; ++w) wpre += s_wsum[w];
    const unsigned int texc = wpre + incl - tsum;
    s_hist[4 * t + 0] = texc;
    s_hist[4 * t + 1] = texc + c0;
    s_hist[4 * t + 2] = texc + c0 + c1;
    s_hist[4 * t + 3] = texc + c0 + c1 + c2;
  }
  __syncthreads();
  // ---- scatter points + orig indices ----
#pragma unroll
  for (int p = 0; p < 16; ++p) {
    const unsigned int slot = atomicAdd(&s_hist[cell[p]], 1u);
    SB[slot]          = arr[3 * p + 0];
    SB[N_ + slot]     = arr[3 * p + 1];
    SB[2 * N_ + slot] = arr[3 * p + 2];
    s_sidx[slot] = (unsigned short)(base + p);
  }
  __threadfence();
  __syncthreads();
  __threadfence();

  // ---- reload sorted points ----
  v2f px[PAIRS], py[PAIRS], pz[PAIRS], d[PAIRS];
  {
    float4 xa[4], ya[4], za[4];
#pragma unroll
    for (int i = 0; i < 4; ++i) {
      xa[i] = *(const float4*)(SB + base + 4 * i);
      ya[i] = *(const float4*)(SB + N_ + base + 4 * i);
      za[i] = *(const float4*)(SB + 2 * N_ + base + 4 * i);
    }
    const float* xf = (const float*)xa;
    const float* yf = (const float*)ya;
    const float* zf = (const float*)za;
#pragma unroll
    for (int j = 0; j < PAIRS; ++j) {
      px[j] = (v2f){xf[2 * j], xf[2 * j + 1]};
      py[j] = (v2f){yf[2 * j], yf[2 * j + 1]};
      pz[j] = (v2f){zf[2 * j], zf[2 * j + 1]};
      d[j] = (v2f){1e10f, 1e10f};
    }
  }
  unsigned int invw[PAIRS];
  {
    const unsigned int* SI = (const unsigned int*)&s_sidx[base];
#pragma unroll
    for (int j = 0; j < PAIRS; ++j) invw[j] = ~SI[j];
  }
  float bx0 = 1e30f, bx1 = -1e30f, by0 = 1e30f, by1 = -1e30f;
  float bz0 = 1e30f, bz1 = -1e30f;
#pragma unroll
  for (int j = 0; j < PAIRS; ++j) {
    bx0 = fminf(bx0, fminf(px[j].x, px[j].y));
    bx1 = fmaxf(bx1, fmaxf(px[j].x, px[j].y));
    by0 = fminf(by0, fminf(py[j].x, py[j].y));
    by1 = fmaxf(by1, fmaxf(py[j].x, py[j].y));
    bz0 = fminf(bz0, fminf(pz[j].x, pz[j].y));
    bz1 = fmaxf(bz1, fmaxf(pz[j].x, pz[j].y));
  }
#pragma unroll
  for (int j = 0; j < PAIRS; ++j) {
    float a0 = px[j].x, a1 = px[j].y;
    float b0 = py[j].x, b1 = py[j].y;
    float c0 = pz[j].x, c1 = pz[j].y;
    pin(a0); pin(a1); pin(b0); pin(b1); pin(c0); pin(c1);
    px[j] = (v2f){a0, a1};
    py[j] = (v2f){b0, b1};
    pz[j] = (v2f){c0, c1};
  }
  float cx = X[0], cy = X[1], cz = X[2];
  float tmax = 1e10f;
  unsigned long long keylow = 0ull;
  bool iwin = false;
  float ccx = 0.f, ccy = 0.f, ccz = 0.f;
  float cap_x = 0.f, cap_y = 0.f, cap_z = 0.f;
  const unsigned int wid = (unsigned int)(t >> 6);
  for (int s = 0; s < 1024; ++s) {
    if (((s - t) & 1023) == 0) { cap_x = cx; cap_y = cy; cap_z = cz; }
    if ((s & 1023) == 1023) {  // epoch-1 flush
      const int o = (b * S_ + (s & ~1023) + t) * 3;
      new_xyz[o + 0] = cap_x;
      new_xyz[o + 1] = cap_y;
      new_xyz[o + 2] = cap_z;
    }
    const int buf = s & 1;
    const float mx = fmaxf(fmaxf(bx0 - cx, cx - bx1), 0.0f);
    const float my = fmaxf(fmaxf(by0 - cy, cy - by1), 0.0f);
    const float mz = fmaxf(fmaxf(bz0 - cz, cz - bz1), 0.0f);
    const float L = (mx * mx + my * my) + mz * mz;
    if (__any(L < tmax)) {
      __builtin_amdgcn_s_setprio(1);
      const v2f c2x = {cx, cx}, c2y = {cy, cy}, c2z = {cz, cz};
#pragma unroll
      for (int j = 0; j < PAIRS; ++j) {
        v2f dx = px[j] - c2x;
        v2f dy = py[j] - c2y;
        v2f dz = pz[j] - c2z;
        v2f sq = (dx * dx + dy * dy) + dz * dz;
        v2f dm;
        dm.x = fminf(d[j].x, sq.x);
        dm.y = fminf(d[j].y, sq.y);
        d[j] = dm;
      }
      const v2f m01 = v2max(d[0], d[1]);
      const v2f m23 = v2max(d[2], d[3]);
      const v2f m45 = v2max(d[4], d[5]);
      const v2f m67 = v2max(d[6], d[7]);
      const v2f m03 = v2max(m01, m23);
      const v2f m47 = v2max(m45, m67);
      const v2f m07 = v2max(m03, m47);
      const float lmax = fmaxf(m07.x, m07.y);
      tmax = lmax;
      unsigned int binv = 0u;
#pragma unroll
      for (int j = 0; j < PAIRS; ++j) {
        const unsigned int lo = invw[j] & 0xFFFFu;
        const unsigned int hi = invw[j] >> 16;
        if (d[j].x == lmax) binv = max(binv, lo);
        if (d[j].y == lmax) binv = max(binv, hi);
      }
#pragma unroll
      for (int j = 0; j < PAIRS; ++j) {
        const unsigned int lo = invw[j] & 0xFFFFu;
        const unsigned int hi = invw[j] >> 16;
        if (lo == binv) { ccx = px[j].x; ccy = py[j].x; ccz = pz[j].x; }
        if (hi == binv) { ccx = px[j].y; ccy = py[j].y; ccz = pz[j].y; }
      }
      const unsigned long long k52 =
          ((unsigned long long)__float_as_uint(lmax) << 20) |
          (unsigned long long)((binv << 4) | wid);
      double dk = __longlong_as_double((long long)k52);
      dk = dppmax<0x111, 0xf>(dk);
      dk = dppmax<0x112, 0xf>(dk);
      dk = dppmax<0x114, 0xf>(dk);
      dk = dppmax<0x118, 0xf>(dk);
      dk = dppmax<0x142, 0xa>(dk);
      dk = dppmax<0x143, 0xc>(dk);
      const long long kb = __double_as_longlong(dk);
      const int rlo = __builtin_amdgcn_readlane((int)(kb & 0xffffffffll), 63);
      const int rhi =
          __builtin_amdgcn_readlane((int)(((unsigned long long)kb) >> 32), 63);
      const unsigned long long wk52 =
          ((unsigned long long)(unsigned int)rhi << 32) | (unsigned int)rlo;
      iwin = (k52 == wk52);
      keylow = wk52;
      __builtin_amdgcn_s_setprio(0);
    }
    if (iwin) {
      atomicMax(&s_k1[buf], ((unsigned long long)s << 52) | keylow);
      s_cc[buf][wid] = make_float4(ccx, ccy, ccz, 0.f);
    }
    __syncthreads();
    const unsigned long long bk = s_k1[buf];
    const int w_win = (int)(bk & 15ull);
    const float4 cc = s_cc[buf][w_win];
    cx = cc.x; cy = cc.y; cz = cc.z;
  }
  // ---- bit-exact state spill ----
  {
    float4* o = (float4*)(dsp + ((size_t)b * 1024 + t) * 16);
    o[0] = make_float4(d[0].x, d[0].y, d[1].x, d[1].y);
    o[1] = make_float4(d[2].x, d[2].y, d[3].x, d[3].y);
    o[2] = make_float4(d[4].x, d[4].y, d[5].x, d[5].y);
    o[3] = make_float4(d[6].x, d[6].y, d[7].x, d[7].y);
    ccsp[b * 1024 + t] = make_float4(ccx, ccy, ccz, iwin ? 1.f : 0.f);
    unsigned int* iv = invsp + ((size_t)b * 1024 + t) * 8;
#pragma unroll
    for (int j = 0; j < PAIRS; ++j) iv[j] = invw[j];
    if ((t & 63) == 0) klsp[b * 16 + wid] = keylow;
    if (t == 0) csp[b] = make_float4(cx, cy, cz, 0.f);
  }
}

// ---------------------------------------------------------------------------
// fps part b body (pragma at compound-statement start; R11 lesson).
// ---------------------------------------------------------------------------
__device__ void fps_b_body(const float* __restrict__ xyz,
                           float* __restrict__ new_xyz,
                           float* __restrict__ sortbuf,
                           float* __restrict__ dsp, float4* __restrict__ ccsp,
                           unsigned int* __restrict__ invsp,
                           unsigned long long* __restrict__ klsp,
                           float4* __restrict__ csp, char* smem) {
#pragma clang fp contract(off)
  const int b = blockIdx.x;
  float* SB = sortbuf + (size_t)b * 3 * N_;
  const int t = threadIdx.x;
  constexpr int PAIRS = N_ / 1024 / 2;
  const int base = t * (2 * PAIRS);
  unsigned long long* s_k1 = (unsigned long long*)smem;
  float4* s_cc = (float4*)(smem + 32);  // [2][16] float4

  v2f px[PAIRS], py[PAIRS], pz[PAIRS], d[PAIRS];
  {
    float4 xa[4], ya[4], za[4];
#pragma unroll
    for (int i = 0; i < 4; ++i) {
      xa[i] = *(const float4*)(SB + base + 4 * i);
      ya[i] = *(const float4*)(SB + N_ + base + 4 * i);
      za[i] = *(const float4*)(SB + 2 * N_ + base + 4 * i);
    }
    const float* xf = (const float*)xa;
    const float* yf = (const float*)ya;
    const float* zf = (const float*)za;
#pragma unroll
    for (int j = 0; j < PAIRS; ++j) {
      px[j] = (v2f){xf[2 * j], xf[2 * j + 1]};
      py[j] = (v2f){yf[2 * j], yf[2 * j + 1]};
      pz[j] = (v2f){zf[2 * j], zf[2 * j + 1]};
    }
  }
  {
    const float4* i4 = (const float4*)(dsp + ((size_t)b * 1024 + t) * 16);
    float4 d0 = i4[0], d1 = i4[1], d2 = i4[2], d3 = i4[3];
    d[0] = (v2f){d0.x, d0.y}; d[1] = (v2f){d0.z, d0.w};
    d[2] = (v2f){d1.x, d1.y}; d[3] = (v2f){d1.z, d1.w};
    d[4] = (v2f){d2.x, d2.y}; d[5] = (v2f){d2.z, d2.w};
    d[6] = (v2f){d3.x, d3.y}; d[7] = (v2f){d3.z, d3.w};
  }
  unsigned int invw[PAIRS];
  {
    const unsigned int* iv = invsp + ((size_t)b * 1024 + t) * 8;
#pragma unroll
    for (int j = 0; j < PAIRS; ++j) invw[j] = iv[j];
  }
  const float4 ccv = ccsp[b * 1024 + t];
  float ccx = ccv.x, ccy = ccv.y, ccz = ccv.z;
  bool iwin = (ccv.w != 0.f);
  const unsigned int wid = (unsigned int)(t >> 6);
  unsigned long long keylow = klsp[b * 16 + wid];
  const float4 cv = csp[b];
  float cx = cv.x, cy = cv.y, cz = cv.z;
  float tmax;
  {
    const v2f m01 = v2max(d[0], d[1]);
    const v2f m23 = v2max(d[2], d[3]);
    const v2f m45 = v2max(d[4], d[5]);
    const v2f m67 = v2max(d[6], d[7]);
    const v2f m03 = v2max(m01, m23);
    const v2f m47 = v2max(m45, m67);
    const v2f m07 = v2max(m03, m47);
    tmax = fmaxf(m07.x, m07.y);
  }
  float bx0 = 1e30f, bx1 = -1e30f, by0 = 1e30f, by1 = -1e30f;
  float bz0 = 1e30f, bz1 = -1e30f;
#pragma unroll
  for (int j = 0; j < PAIRS; ++j) {
    bx0 = fminf(bx0, fminf(px[j].x, px[j].y));
    bx1 = fmaxf(bx1, fmaxf(px[j].x, px[j].y));
    by0 = fminf(by0, fminf(py[j].x, py[j].y));
    by1 = fmaxf(by1, fmaxf(py[j].x, py[j].y));
    bz0 = fminf(bz0, fminf(pz[j].x, pz[j].y));
    bz1 = fmaxf(bz1, fmaxf(pz[j].x, pz[j].y));
  }
#pragma unroll
  for (int j = 0; j < PAIRS; ++j) {
    float a0 = px[j].x, a1 = px[j].y;
    float b0 = py[j].x, b1 = py[j].y;
    float c0 = pz[j].x, c1 = pz[j].y;
    pin(a0); pin(a1); pin(b0); pin(b1); pin(c0); pin(c1);
    px[j] = (v2f){a0, a1};
    py[j] = (v2f){b0, b1};
    pz[j] = (v2f){c0, c1};
  }
  if (t == 0) { s_k1[0] = 0ull; s_k1[1] = 0ull; }  // stale tags < 1024 lose
  __syncthreads();
  float cap_x = 0.f, cap_y = 0.f, cap_z = 0.f;
  for (int s = 1024; s < S_; ++s) {
    if (((s - t) & 1023) == 0) { cap_x = cx; cap_y = cy; cap_z = cz; }
    if ((s & 1023) == 1023) {  // epoch-2 flush
      const int o = (b * S_ + (s & ~1023) + t) * 3;
      new_xyz[o + 0] = cap_x;
      new_xyz[o + 1] = cap_y;
      new_xyz[o + 2] = cap_z;
    }
    if (s == S_ - 1) break;
    const int buf = s & 1;
    const float mx = fmaxf(fmaxf(bx0 - cx, cx - bx1), 0.0f);
    const float my = fmaxf(fmaxf(by0 - cy, cy - by1), 0.0f);
    const float mz = fmaxf(fmaxf(bz0 - cz, cz - bz1), 0.0f);
    const float L = (mx * mx + my * my) + mz * mz;
    if (__any(L < tmax)) {
      __builtin_amdgcn_s_setprio(1);
      const v2f c2x = {cx, cx}, c2y = {cy, cy}, c2z = {cz, cz};
#pragma unroll
      for (int j = 0; j < PAIRS; ++j) {
        v2f dx = px[j] - c2x;
        v2f dy = py[j] - c2y;
        v2f dz = pz[j] - c2z;
        v2f sq = (dx * dx + dy * dy) + dz * dz;
        v2f dm;
        dm.x = fminf(d[j].x, sq.x);
        dm.y = fminf(d[j].y, sq.y);
        d[j] = dm;
      }
      const v2f m01 = v2max(d[0], d[1]);
      const v2f m23 = v2max(d[2], d[3]);
      const v2f m45 = v2max(d[4], d[5]);
      const v2f m67 = v2max(d[6], d[7]);
      const v2f m03 = v2max(m01, m23);
      const v2f m47 = v2max(m45, m67);
      const v2f m07 = v2max(m03, m47);
      const float lmax = fmaxf(m07.x, m07.y);
      tmax = lmax;
      unsigned int binv = 0u;
#pragma unroll
      for (int j = 0; j < PAIRS; ++j) {
        const unsigned int lo = invw[j] & 0xFFFFu;
        const unsigned int hi = invw[j] >> 16;
        if (d[j].x == lmax) binv = max(binv, lo);
        if (d[j].y == lmax) binv = max(binv, hi);
      }
#pragma unroll
      for (int j = 0; j < PAIRS; ++j) {
        const unsigned int lo = invw[j] & 0xFFFFu;
        const unsigned int hi = invw[j] >> 16;
        if (lo == binv) { ccx = px[j].x; ccy = py[j].x; ccz = pz[j].x; }
        if (hi == binv) { ccx = px[j].y; ccy = py[j].y; ccz = pz[j].y; }
      }
      const unsigned long long k52 =
          ((unsigned long long)__float_as_uint(lmax) << 20) |
          (unsigned long long)((binv << 4) | wid);
      double dk = __longlong_as_double((long long)k52);
      dk = dppmax<0x111, 0xf>(dk);
      dk = dppmax<0x112, 0xf>(dk);
      dk = dppmax<0x114, 0xf>(dk);
      dk = dppmax<0x118, 0xf>(dk);
      dk = dppmax<0x142, 0xa>(dk);
      dk = dppmax<0x143, 0xc>(dk);
      const long long kb = __double_as_longlong(dk);
      const int rlo = __builtin_amdgcn_readlane((int)(kb & 0xffffffffll), 63);
      const int rhi =
          __builtin_amdgcn_readlane((int)(((unsigned long long)kb) >> 32), 63);
      const unsigned long long wk52 =
          ((unsigned long long)(unsigned int)rhi << 32) | (unsigned int)rlo;
      iwin = (k52 == wk52);
      keylow = wk52;
      __builtin_amdgcn_s_setprio(0);
    }
    if (iwin) {
      atomicMax(&s_k1[buf], ((unsigned long long)s << 52) | keylow);
      s_cc[buf * 16 + wid] = make_float4(ccx, ccy, ccz, 0.f);
    }
    __syncthreads();
    const unsigned long long bk = s_k1[buf];
    const int w_win = (int)(bk & 15ull);
    const float4 cc = s_cc[buf * 16 + w_win];
    cx = cc.x; cy = cc.y; cz = cc.z;
  }
}

// ---------------------------------------------------------------------------
// kNN core @1024 threads (R10-verified tag/atomic/DPP scheme) + FUSED conv1
// stats (v13): after the selection loop, the block stages its 16 neighbors'
// C0 channels in LDS (aliasing the dead sd region), computes y1 with the
// IDENTICAL bias-then-ascending-c fmaf chain as the original conv1 kernel
// (thread t -> co=t&127, k=t>>7 and k+8), float2-tree-reduces the per-co
// sum/sumsq over the 8 sharing threads, and atomicAdds into the slot-sliced
// stats (stats order was already atomic-nondeterministic; tolerance covers).
// ---------------------------------------------------------------------------
__device__ __forceinline__ void knn_core(
    float* sd, unsigned long long* s_kd, int* s_widx,
    const float* __restrict__ xyz, const float* __restrict__ new_xyz,
    int* __restrict__ knn_idx, int q, int b, const float* __restrict__ feat,
    const float* __restrict__ W1t, const float* __restrict__ b1,
    float* __restrict__ stats1, int slot) {
  const int t = threadIdx.x;
  if (t == 0) { s_kd[0] = ~0ull; s_kd[1] = ~0ull; }
  const float qx = new_xyz[q * 3 + 0];
  const float qy = new_xyz[q * 3 + 1];
  const float qz = new_xyz[q * 3 + 2];
  const float* X = xyz + (size_t)b * N_ * 3;
  float lmin = 1e30f;
  int lidx = -1;
  for (int j = 0; j < N_ / 1024; ++j) {
    int i = t + j * 1024;
    float dx = X[i * 3 + 0] - qx;
    float dy = X[i * 3 + 1] - qy;
    float dz = X[i * 3 + 2] - qz;
    float dsq = fmaf(dx, dx, fmaf(dy, dy, dz * dz));
    sd[i] = dsq;
    if (dsq < lmin) { lmin = dsq; lidx = i; }
  }
  __syncthreads();
  for (int r = 0; r < K_; ++r) {
    const unsigned long long k =
        ((unsigned long long)(7 - (r >> 1)) << 60) |
        ((unsigned long long)__float_as_uint(lmin) << 28) |
        (unsigned int)(lidx & 0x0FFFFFFF);
    double dk = __longlong_as_double((long long)k);
    dk = dppmin<0x111, 0xf>(dk);
    dk = dppmin<0x112, 0xf>(dk);
    dk = dppmin<0x114, 0xf>(dk);
    dk = dppmin<0x118, 0xf>(dk);
    dk = dppmin<0x142, 0xa>(dk);
    dk = dppmin<0x143, 0xc>(dk);
    const long long kb = __double_as_longlong(dk);
    const int rlo = __builtin_amdgcn_readlane((int)(kb & 0xffffffffll), 63);
    const int rhi =
        __builtin_amdgcn_readlane((int)(((unsigned long long)kb) >> 32), 63);
    const unsigned long long wk =
        ((unsigned long long)(unsigned int)rhi << 32) | (unsigned int)rlo;
    if ((t & 63) == 0) atomicMin(&s_kd[r & 1], wk);
    __syncthreads();
    const unsigned long long bk = s_kd[r & 1];
    const int wi = (int)(bk & 0x0FFFFFFFull);
    if (t == 0) {
      knn_idx[q * K_ + r] = wi;
      s_widx[r] = wi;
    }
    if (wi == lidx && r < K_ - 1) {  // last-round rescan result unused
      sd[wi] = 1e30f;
      lmin = 1e30f; lidx = -1;
      for (int j = 0; j < N_ / 1024; ++j) {
        int i = t + j * 1024;
        float dv = sd[i];
        if (dv < lmin) { lmin = dv; lidx = i; }
      }
    }
  }
  // ---- fused conv1 stats (sd region is dead; alias sinT + sred) ----
  __syncthreads();
  float* sinT = sd;                      // [C0][K] = 2048 floats
  float2* sred = (float2*)(sd + 2048);   // 1024 float2
#pragma unroll
  for (int u = 0; u < 2; ++u) {
    const int e = 2 * t + u;
    const int c = e >> 4, kk = e & 15;
    const int i = s_widx[kk];
    float v;
    if (c < 3)
      v = xyz[((size_t)b * N_ + i) * 3 + c] - (c == 0 ? qx : (c == 1 ? qy : qz));
    else
      v = feat[((size_t)b * N_ + i) * D_ + (c - 3)];
    sinT[c * 16 + kk] = v;
  }
  __syncthreads();
  const int co = t & 127, g = t >> 7;  // outputs (co,g) and (co,g+8)
  const float bias = b1[co];
  float a0 = bias, a1 = bias;
  for (int c = 0; c < C0_; ++c) {
    const float w = W1t[c * C1_ + co];
    a0 = fmaf(w, sinT[c * 16 + g], a0);
    a1 = fmaf(w, sinT[c * 16 + g + 8], a1);
  }
  sred[t] = make_float2(a0 + a1, fmaf(a0, a0, a1 * a1));
  __syncthreads();
  if (t < 512) {
    float2 o = sred[t + 512], m = sred[t];
    sred[t] = make_float2(m.x + o.x, m.y + o.y);
  }
  __syncthreads();
  if (t < 256) {
    float2 o = sred[t + 256], m = sred[t];
    sred[t] = make_float2(m.x + o.x, m.y + o.y);
  }
  __syncthreads();
  if (t < 128) {
    float2 o = sred[t + 128], m = sred[t];
    float* st = stats1 + (size_t)slot * (2 * C1_);
    atomicAdd(&st[t], m.x + o.x);
    atomicAdd(&st[C1_ + t], m.y + o.y);
  }
}

// ---------------------------------------------------------------------------
// Fused launch 2: blocks 0..B_-1 resume fps (iters 1024..2047); blocks
// B_.. run kNN+conv1 for first-half queries. Roles independent; 1 block/CU.
// ---------------------------------------------------------------------------
__global__ __attribute__((amdgpu_flat_work_group_size(1024, 1024),
                          amdgpu_waves_per_eu(4, 4)))
void fused_b_kernel(const float* __restrict__ xyz, float* __restrict__ new_xyz,
                    float* __restrict__ sortbuf, float* __restrict__ dsp,
                    float4* __restrict__ ccsp, unsigned int* __restrict__ invsp,
                    unsigned long long* __restrict__ klsp,
                    float4* __restrict__ csp, int* __restrict__ knn_idx,
                    const float* __restrict__ feat,
                    const float* __restrict__ W1t,
                    const float* __restrict__ b1, float* __restrict__ stats1) {
  __shared__ __align__(16) char smem[N_ * 4 + 16 + 64];  // sd | s_kd | s_widx
  if (blockIdx.x >= B_) {
    const int idx = blockIdx.x - B_;
    const int b = idx >> 10;
    const int s = idx & 1023;  // first half
    knn_core((float*)smem, (unsigned long long*)(smem + N_ * 4),
             (int*)(smem + N_ * 4 + 16), xyz, new_xyz, knn_idx, b * S_ + s, b,
             feat, W1t, b1, stats1, (int)(blockIdx.x & (NSLOT - 1)));
    return;
  }
  fps_b_body(xyz, new_xyz, sortbuf, dsp, ccsp, invsp, klsp, csp, smem);
}

// ---------------------------------------------------------------------------
// kNN+conv1 second half: standalone.
// ---------------------------------------------------------------------------
__global__ __attribute__((amdgpu_flat_work_group_size(1024, 1024)))
void knn2_kernel(const float* __restrict__ xyz,
                 const float* __restrict__ new_xyz, int* __restrict__ knn_idx,
                 const float* __restrict__ feat, const float* __restrict__ W1t,
                 const float* __restrict__ b1, float* __restrict__ stats1) {
  __shared__ float sd[N_];
  __shared__ unsigned long long s_kd[2];
  __shared__ int s_widx[K_];
  const int idx = blockIdx.x;
  const int b = idx >> 10;
  const int s = 1024 + (idx & 1023);
  knn_core(sd, s_kd, s_widx, xyz, new_xyz, knn_idx, b * S_ + s, b, feat, W1t,
           b1, stats1, (int)(blockIdx.x & (NSLOT - 1)));
}

// ---------------------------------------------------------------------------
// Transpose weights + zero stats (unchanged).
// ---------------------------------------------------------------------------
__global__ __launch_bounds__(256) void prep_kernel(const float* __restrict__ W1,
                                                   const float* __restrict__ W2,
                                                   float* __restrict__ W1t,
                                                   float* __restrict__ W2t,
                                                   float* __restrict__ stats) {
  int e = blockIdx.x * 256 + threadIdx.x;
  stats[e] = 0.0f;
  if (e < C1_ * C0_) {
    int co = e / C0_, c = e % C0_;
    W1t[c * C1_ + co] = W1[e];
  } else {
    int e2 = e - C1_ * C0_;
    int co = e2 / C1_, c = e2 % C1_;
    W2t[c * C2_ + co] = W2[e2];
  }
}

__global__ void finalize1_kernel(const float* __restrict__ stats1,
                                 const float* __restrict__ gamma1,
                                 const float* __restrict__ beta1,
                                 float* __restrict__ ss1) {
  int t = threadIdx.x;
  float s = 0.f, sq = 0.f;
  for (int w = 0; w < NSLOT; ++w) {
    s += stats1[w * 2 * C1_ + t];
    sq += stats1[w * 2 * C1_ + C1_ + t];
  }
  const float M = (float)(B_ * S_ * K_);
  float m = s / M;
  float v = fmaxf(sq / M - m * m, 0.f);
  float sc = gamma1[t] * rsqrtf(v + 1e-5f);
  ss1[t] = sc;
  ss1[C1_ + t] = fmaf(-m, sc, beta1[t]);
}

// ---------------------------------------------------------------------------
// conv2 (unchanged).
// ---------------------------------------------------------------------------
__global__ __launch_bounds__(256) void conv2_kernel(
    const float* __restrict__ xyz, const float* __restrict__ feat,
    const float* __restrict__ new_xyz, const int* __restrict__ knn,
    const float* __restrict__ W1t, const float* __restrict__ b1,
    const float* __restrict__ ss1, const float* __restrict__ W2t,
    const float* __restrict__ b2, float* __restrict__ maxv,
    float* __restrict__ minv, float* __restrict__ stats2) {
  __shared__ __align__(16) float sinT[C0_][K_];
  __shared__ __align__(16) float sh1T[C1_][20];
  __shared__ int sidx[K_];
  const int t = threadIdx.x;
  float psum = 0.f, psumsq = 0.f;
  const int QPB = (B_ * S_) / 1024;
  for (int qq = 0; qq < QPB; ++qq) {
    const int q = blockIdx.x * QPB + qq;
    const int b = q / S_;
    if (t < K_) sidx[t] = knn[q * K_ + t];
    __syncthreads();
    const float nx = new_xyz[q * 3 + 0];
    const float ny = new_xyz[q * 3 + 1];
    const float nz = new_xyz[q * 3 + 2];
    for (int e = t; e < K_ * C0_; e += 256) {
      int c = e >> 4, kk = e & 15;
      int i = sidx[kk];
      float v;
      if (c < 3)
        v = xyz[((size_t)b * N_ + i) * 3 + c] - (c == 0 ? nx : (c == 1 ? ny : nz));
      else
        v = feat[((size_t)b * N_ + i) * D_ + (c - 3)];
      sinT[c][kk] = v;
    }
    __syncthreads();
    {
      const int co = t & 127, kh = t >> 7;
      float acc[8];
      float bias = b1[co];
#pragma unroll
      for (int k = 0; k < 8; ++k) acc[k] = bias;
      for (int c = 0; c < C0_; ++c) {
        float w = W1t[c * C1_ + co];
        float4 xa = *(const float4*)&sinT[c][kh * 8];
        float4 xb = *(const float4*)&sinT[c][kh * 8 + 4];
        acc[0] = fmaf(w, xa.x, acc[0]);
        acc[1] = fmaf(w, xa.y, acc[1]);
        acc[2] = fmaf(w, xa.z, acc[2]);
        acc[3] = fmaf(w, xa.w, acc[3]);
        acc[4] = fmaf(w, xb.x, acc[4]);
        acc[5] = fmaf(w, xb.y, acc[5]);
        acc[6] = fmaf(w, xb.z, acc[6]);
        acc[7] = fmaf(w, xb.w, acc[7]);
      }
      float sc = ss1[co], sh = ss1[C1_ + co];
#pragma unroll
      for (int k = 0; k < 8; ++k) {
        float h = fmaxf(fmaf(acc[k], sc, sh), 0.f);
        sh1T[co][kh * 8 + k] = h;
      }
    }
    __syncthreads();
    {
      float acc2[16];
      float bias2 = b2[t];
#pragma unroll
      for (int k = 0; k < 16; ++k) acc2[k] = bias2;
      for (int c = 0; c < C1_; ++c) {
        float w = W2t[c * C2_ + t];
        float4 h0 = *(const float4*)&sh1T[c][0];
        float4 h1 = *(const float4*)&sh1T[c][4];
        float4 h2 = *(const float4*)&sh1T[c][8];
        float4 h3 = *(const float4*)&sh1T[c][12];
        acc2[0] = fmaf(w, h0.x, acc2[0]);
        acc2[1] = fmaf(w, h0.y, acc2[1]);
        acc2[2] = fmaf(w, h0.z, acc2[2]);
        acc2[3] = fmaf(w, h0.w, acc2[3]);
        acc2[4] = fmaf(w, h1.x, acc2[4]);
        acc2[5] = fmaf(w, h1.y, acc2[5]);
        acc2[6] = fmaf(w, h1.z, acc2[6]);
        acc2[7] = fmaf(w, h1.w, acc2[7]);
        acc2[8] = fmaf(w, h2.x, acc2[8]);
        acc2[9] = fmaf(w, h2.y, acc2[9]);
        acc2[10] = fmaf(w, h2.z, acc2[10]);
        acc2[11] = fmaf(w, h2.w, acc2[11]);
        acc2[12] = fmaf(w, h3.x, acc2[12]);
        acc2[13] = fmaf(w, h3.y, acc2[13]);
        acc2[14] = fmaf(w, h3.z, acc2[14]);
        acc2[15] = fmaf(w, h3.w, acc2[15]);
      }
      float mx = acc2[0], mn = acc2[0];
#pragma unroll
      for (int k = 0; k < 16; ++k) {
        psum += acc2[k];
        psumsq = fmaf(acc2[k], acc2[k], psumsq);
        mx = fmaxf(mx, acc2[k]);
        mn = fminf(mn, acc2[k]);
      }
      maxv[(size_t)q * C2_ + t] = mx;
      minv[(size_t)q * C2_ + t] = mn;
    }
    __syncthreads();
  }
  float* st = stats2 + (size_t)(blockIdx.x & (NSLOT - 1)) * (2 * C2_);
  atomicAdd(&st[t], psum);
  atomicAdd(&st[C2_ + t], psumsq);
}

__global__ void finalize2_kernel(const float* __restrict__ stats2,
                                 const float* __restrict__ gamma2,
                                 const float* __restrict__ beta2,
                                 float* __restrict__ ss2) {
  int t = threadIdx.x;
  float s = 0.f, sq = 0.f;
  for (int w = 0; w < NSLOT; ++w) {
    s += stats2[w * 2 * C2_ + t];
    sq += stats2[w * 2 * C2_ + C2_ + t];
  }
  const float M = (float)(B_ * S_ * K_);
  float m = s / M;
  float v = fmaxf(sq / M - m * m, 0.f);
  float sc = gamma2[t] * rsqrtf(v + 1e-5f);
  ss2[t] = sc;
  ss2[C2_ + t] = fmaf(-m, sc, beta2[t]);
}

// max_k relu(bn(y)) == relu(bn(max_k y)) for scale>=0 (min_k for scale<0)
__global__ __launch_bounds__(256) void out_kernel(const float* __restrict__ maxv,
                                                  const float* __restrict__ minv,
                                                  const float* __restrict__ ss2,
                                                  float* __restrict__ out2) {
  int e = blockIdx.x * 256 + threadIdx.x;
  int co = e & (C2_ - 1);
  float sc = ss2[co], sh = ss2[C2_ + co];
  float v = (sc >= 0.f) ? maxv[e] : minv[e];
  out2[e] = fmaxf(fmaf(v, sc, sh), 0.f);
}

extern "C" void kernel_launch(void* const* d_in, const int* in_sizes, int n_in,
                              void* d_out, int out_size, void* d_ws, size_t ws_size,
                              hipStream_t stream) {
  (void)in_sizes; (void)n_in; (void)out_size; (void)ws_size;
  const float* xyz = (const float*)d_in[0];
  const float* feat = (const float*)d_in[1];
  const float* W1 = (const float*)d_in[2];
  const float* b1 = (const float*)d_in[3];
  const float* gamma1 = (const float*)d_in[4];
  const float* beta1 = (const float*)d_in[5];
  const float* W2 = (const float*)d_in[6];
  const float* b2 = (const float*)d_in[7];
  const float* gamma2 = (const float*)d_in[8];
  const float* beta2 = (const float*)d_in[9];

  float* out = (float*)d_out;
  float* new_xyz = out;                 // [B,S,3]
  float* out2 = out + B_ * S_ * 3;      // [B,S,C2]

  float* ws = (float*)d_ws;
  float* stats1 = ws;                              // 64*256
  float* stats2 = stats1 + NSLOT * 2 * C1_;        // 64*512
  float* ss1 = stats2 + NSLOT * 2 * C2_;           // 256
  float* ss2 = ss1 + 2 * C1_;                      // 512
  float* W1t = ss2 + 2 * C2_;                      // 16384
  float* W2t = W1t + C1_ * C0_;                    // 32768
  int* knn = (int*)(W2t + (size_t)C2_ * C1_);      // B*S*K ints
  float* maxv = (float*)(knn + B_ * S_ * K_);      // B*S*C2
  float* minv = maxv + (size_t)B_ * S_ * C2_;      // B*S*C2
  // fps staging aliases dead conv2 outputs (conv2 runs after all fps/knn):
  //   sortbuf -> maxv region; spill -> minv region.
  float* sortbuf = maxv;
  float* dsp = minv;
  float4* ccsp = (float4*)(minv + 65536);
  unsigned int* invsp = (unsigned int*)(minv + 65536 + 16384);
  unsigned long long* klsp =
      (unsigned long long*)(minv + 65536 + 16384 + 32768);
  float4* csp = (float4*)(minv + 65536 + 16384 + 32768 + 2 * B_ * 16);

  prep_kernel<<<192, 256, 0, stream>>>(W1, W2, W1t, W2t, stats1);
  fps_a_kernel<<<B_, 1024, 0, stream>>>(xyz, new_xyz, sortbuf, dsp, ccsp,
                                        invsp, klsp, csp);
  fused_b_kernel<<<B_ + B_ * 1024, 1024, 0, stream>>>(
      xyz, new_xyz, sortbuf, dsp, ccsp, invsp, klsp, csp, knn, feat, W1t, b1,
      stats1);
  knn2_kernel<<<B_ * 1024, 1024, 0, stream>>>(xyz, new_xyz, knn, feat, W1t,
                                              b1, stats1);
  finalize1_kernel<<<1, 128, 0, stream>>>(stats1, gamma1, beta1, ss1);
  conv2_kernel<<<1024, 256, 0, stream>>>(xyz, feat, new_xyz, knn, W1t, b1, ss1,
                                         W2t, b2, maxv, minv, stats2);
  finalize2_kernel<<<1, 256, 0, stream>>>(stats2, gamma2, beta2, ss2);
  out_kernel<<<(B_ * S_ * C2_) / 256, 256, 0, stream>>>(maxv, minv, ss2, out2);
}